// Round 3
// baseline (5463.621 us; speedup 1.0000x reference)
//
#include <hip/hip_runtime.h>
#include <hip/hip_bf16.h>
#include <math.h>

#define T_ 128
#define B_ 256
#define BP 512     // 2B (party batch)
#define D_ 1024
#define H_ 150
#define G_ 600     // 4H
#define O_ 300     // 2H
#define ROWS 16    // batch rows per scan block (one MFMA M-tile)
#define NT_ 38     // n-tiles of 16 covering 600 (608)
#define KT_ 5      // k-tiles of 32 covering 150 (160)
#define KTX 10     // k-tiles of 32 covering 300 (320) for fused layer-1 xW
#define KAP 40     // layer-1 plane k-blocks of 8 (320/8)
#define HSTR 168   // h hi/lo plane row stride in ushorts
#define GST 620    // gs row stride in floats
#define TPB 512    // scan threads per block (8 waves)
#define EIT 5      // update-phase elems/thread: 16*160/512
#define NTB 38     // GEMM B n-tiles packed

typedef float v4f    __attribute__((ext_vector_type(4)));
typedef short bf16x8 __attribute__((ext_vector_type(8)));
typedef float f32x4  __attribute__((ext_vector_type(4)));
typedef unsigned int u32x4 __attribute__((ext_vector_type(4)));
union HU { u32x4 u; bf16x8 h; };

// ---------------- NEW workspace layout (4-byte words) ----------------
// inv | wpk (scan Whh frags, 8 combos) | bw1 (layer-1 Wih frags, 4 combos) |
// HPK (packed h planes: rnn hi/lo, pr hi/lo; BW0 + Upk aliased here pre-scan0) |
// X (4 slots, layer-0 xW; X[0] aliased as U_p scratch during scan1)
static const size_t N_INV   = 0;                          // 65,536 words
static const size_t N_WPK   = 65536;                      // +778,240
static const size_t N_BW1   = N_WPK + 778240;             // +778,240 (4 x 194,560)
static const size_t N_HPK   = N_BW1 + 778240;             // +31,457,280
static const size_t N_X     = N_HPK + 31457280;           // +78,643,200
static const size_t N_TOTAL = N_X + 78643200 + 256;       // ~446.9 MB

static const size_t WPS      = (size_t)NT_ * KT_ * 2 * 512;  // shorts per Whh combo
static const size_t BW1_STR  = (size_t)KTX * NTB * 2 * 512;  // shorts per L1 Wih combo
static const size_t BW0_STR  = 32ull * NTB * 2 * 512;        // shorts per L0 Wih combo
// plane sizes in shorts
static const size_t RNN_PL   = 2048ull * KAP * 128;          // 10,485,760
static const size_t PR_PL    = 4096ull * KAP * 128;          // 20,971,520

// ---------------- legacy layout (fallback only) ----------------
static const size_t INV_OFF   = 0;
static const size_t WIHT0_OFF = 65536;
static const size_t WIHT1_OFF = WIHT0_OFF + 4ull * 1024 * 600;
static const size_t WPK_OFF   = WIHT1_OFF + 4ull * 300 * 600;
static const size_t WPK_WORDS = 8ull * NT_ * KT_ * 2 * 512 / 2;
static const size_t XW_OFF    = WPK_OFF + WPK_WORDS;
static const size_t XSLOT     = 32768ull * 600;
static size_t hrnn_off(int nslots) { return XW_OFF + (size_t)nslots * XSLOT; }
static size_t hpr_off(int nslots)  { return hrnn_off(nslots) + 32768ull * 300; }

// ---------------- fast transcendentals ----------------
__device__ __forceinline__ float fsig(float x) {
    return __builtin_amdgcn_rcpf(1.f + __expf(-x));
}
__device__ __forceinline__ float ftanh(float x) {
    float xc = fminf(fmaxf(x, -15.f), 15.f);
    float e = __expf(-2.f * xc);
    return (1.f - e) * __builtin_amdgcn_rcpf(1.f + e);
}

// ---------------- inverse map ----------------
__global__ void k_pos(const int* __restrict__ qmask, int* __restrict__ inv) {
    int b = threadIdx.x;
    for (int p = 0; p < T_; ++p) {
        inv[p * BP + b] = -1;
        inv[p * BP + B_ + b] = -1;
    }
    int c0 = 0, c1 = 0;
    for (int t = 0; t < T_; ++t) {
        int s = qmask[(t * B_ + b) * 2 + 1];
        int p = s ? c1++ : c0++;
        inv[p * BP + s * B_ + b] = t * B_ + b;
    }
}

// ---------------- zero a word range ----------------
__global__ void k_zero(unsigned int* __restrict__ p, int n4) {
    int gid = blockIdx.x * 256 + threadIdx.x;
    if (gid < n4) *(u32x4*)(p + (size_t)gid * 4) = (u32x4){0, 0, 0, 0};
}

// ---------------- transpose (legacy fallback) ----------------
__global__ void k_transpose(const float* __restrict__ src, float* __restrict__ dst,
                            int K) {
    int idx = blockIdx.x * 256 + threadIdx.x;
    int total = K * G_;
    if (idx < total) {
        int k = idx / G_, g = idx - k * G_;
        dst[idx] = src[(size_t)g * K + k];
    }
}

// ---------------- pack Whh into scan B-fragment hi/lo layout ----------
struct PackArgs { const float* whh[8]; };
__global__ void k_pack(PackArgs pa, unsigned short* __restrict__ wpk) {
    int gid = blockIdx.x * 256 + threadIdx.x;
    int lane = gid & 63;
    int q = gid >> 6;
    int kt = q % KT_; q /= KT_;
    int nt = q % NT_; q /= NT_;
    if (q >= 8) return;
    const float* W = pa.whh[q];
    int col = nt * 16 + (lane & 15);
    int kbase = kt * 32 + (lane >> 4) * 8;
    size_t base = ((((size_t)q * NT_ + nt) * KT_ + kt) * 2) * 512 + (size_t)lane * 8;
    for (int j = 0; j < 8; ++j) {
        int k = kbase + j;
        float v = (col < G_ && k < H_) ? W[(size_t)col * H_ + k] : 0.f;
        unsigned u = __float_as_uint(v);
        unsigned short hi = (unsigned short)(u >> 16);
        float hf = __uint_as_float(u & 0xffff0000u);
        unsigned short lo = (unsigned short)(__float_as_uint(v - hf) >> 16);
        wpk[base + j] = hi;
        wpk[base + 512 + j] = lo;
    }
}

// ---------------- pack Wih[600][K] into GEMM B-fragment hi/lo layout --------------
// out layout: [kt][nt(38)][hi/lo][lane][8]; zeros for k>=K or col>=600
__global__ void k_packB(const float* __restrict__ W, int K, int KT,
                        unsigned short* __restrict__ out) {
    int gid = blockIdx.x * 256 + threadIdx.x;
    int lane = gid & 63, q = gid >> 6;
    int kt = q % KT, nt = q / KT;
    if (nt >= NTB) return;
    int col = nt * 16 + (lane & 15);
    int kb = kt * 32 + (lane >> 4) * 8;
    size_t base = ((size_t)(kt * NTB + nt) * 2) * 512 + (size_t)lane * 8;
    bf16x8 h8 = {0, 0, 0, 0, 0, 0, 0, 0};
    bf16x8 l8 = {0, 0, 0, 0, 0, 0, 0, 0};
#pragma unroll
    for (int j = 0; j < 8; ++j) {
        int k = kb + j;
        float v = (col < G_ && k < K) ? W[(size_t)col * K + k] : 0.f;
        unsigned u = __float_as_uint(v);
        h8[j] = (short)(u >> 16);
        float hf = __uint_as_float(u & 0xffff0000u);
        l8[j] = (short)(__float_as_uint(v - hf) >> 16);
    }
    *(bf16x8*)(out + base) = h8;
    *(bf16x8*)(out + base + 512) = l8;
}

// ---------------- pack U half (16384 x 1024) into A-fragment planes ----------
// off(m,k) = (((m>>4)*128 + (k>>3))*16 + (m&15))*8 + (k&7)
__global__ void k_packU(const float* __restrict__ A, unsigned short* __restrict__ hi,
                        unsigned short* __restrict__ lo) {
    int gid = blockIdx.x * 256 + threadIdx.x;
    int kc = gid & 127, rr = gid >> 7;
    const float* ap = A + (size_t)rr * 1024 + kc * 8;
    size_t off = ((size_t)((rr >> 4) * 128 + kc) * 16 + (rr & 15)) * 8;
    bf16x8 h8, l8;
#pragma unroll
    for (int j = 0; j < 8; ++j) {
        float v = ap[j];
        unsigned u = __float_as_uint(v);
        h8[j] = (short)(u >> 16);
        float hf = __uint_as_float(u & 0xffff0000u);
        l8[j] = (short)(__float_as_uint(v - hf) >> 16);
    }
    *(bf16x8*)(hi + off) = h8;
    *(bf16x8*)(lo + off) = l8;
}

// ---------------- MFMA GEMM (layer 0): C[M,600] = A[M,1024] @ W^T + bias ----------
#define LOADK(kt_, S)                                                          \
  {                                                                            \
    if (MODE == 0) {                                                           \
      _Pragma("unroll") for (int mi = 0; mi < 4; ++mi) {                       \
        size_t aoff = ((size_t)((m0 >> 4) + mi) * KA + (kt_) * 4 + quad);      \
        aoff = (aoff * 16 + col16) * 8;                                        \
        a_h##S[mi] = *(const bf16x8*)(Ahi + aoff);                             \
        a_l##S[mi] = *(const bf16x8*)(Alo + aoff);                             \
      }                                                                        \
    } else {                                                                   \
      _Pragma("unroll") for (int mi = 0; mi < 4; ++mi) {                       \
        const unsigned int* ap =                                               \
            Aw + (size_t)(m0 + mi * 16 + col16) * KA + (kt_) * 32 + quad * 8;  \
        u32x4 w0 = *(const u32x4*)ap;                                          \
        u32x4 w1 = *(const u32x4*)(ap + 4);                                    \
        HU hh, ll;                                                             \
        hh.u.x = (w0.x >> 16) | (w0.y & 0xffff0000u);                          \
        hh.u.y = (w0.z >> 16) | (w0.w & 0xffff0000u);                          \
        hh.u.z = (w1.x >> 16) | (w1.y & 0xffff0000u);                          \
        hh.u.w = (w1.z >> 16) | (w1.w & 0xffff0000u);                          \
        ll.u.x = (w0.x & 0xffffu) | (w0.y << 16);                              \
        ll.u.y = (w0.z & 0xffffu) | (w0.w << 16);                              \
        ll.u.z = (w1.x & 0xffffu) | (w1.y << 16);                              \
        ll.u.w = (w1.z & 0xffffu) | (w1.w << 16);                              \
        a_h##S[mi] = hh.h;                                                     \
        a_l##S[mi] = ll.h;                                                     \
      }                                                                        \
    }                                                                          \
    _Pragma("unroll") for (int ni = 0; ni < 4; ++ni) {                         \
      if (bnv[ni]) {                                                           \
        size_t bo = ((size_t)((kt_) * NTB + nt0 + ni) * 2) * 512 + lane * 8;   \
        b_h##S[ni] = *(const bf16x8*)(Bpk + bo);                               \
        b_l##S[ni] = *(const bf16x8*)(Bpk + bo + 512);                         \
      }                                                                        \
    }                                                                          \
  }

#define MMK(S)                                                                 \
  _Pragma("unroll") for (int mi = 0; mi < 4; ++mi)                             \
    _Pragma("unroll") for (int ni = 0; ni < 4; ++ni) {                         \
      acc[mi][ni] = __builtin_amdgcn_mfma_f32_16x16x32_bf16(                   \
          a_h##S[mi], b_h##S[ni], acc[mi][ni], 0, 0, 0);                       \
      acc[mi][ni] = __builtin_amdgcn_mfma_f32_16x16x32_bf16(                   \
          a_h##S[mi], b_l##S[ni], acc[mi][ni], 0, 0, 0);                       \
      acc[mi][ni] = __builtin_amdgcn_mfma_f32_16x16x32_bf16(                   \
          a_l##S[mi], b_h##S[ni], acc[mi][ni], 0, 0, 0);                       \
    }

template<int MODE, int KTN, int KA>
__global__ __launch_bounds__(256) void k_mgemm(const unsigned short* __restrict__ Ahi,
                                               const unsigned short* __restrict__ Alo,
                                               const unsigned int* __restrict__ Aw,
                                               const unsigned short* __restrict__ Bpk,
                                               const float* __restrict__ bias,
                                               float* __restrict__ C) {
    int tid = threadIdx.x, lane = tid & 63, wv = tid >> 6;
    int col16 = lane & 15, quad = lane >> 4;
    int n0 = blockIdx.x * 128 + (wv & 1) * 64;
    int m0 = blockIdx.y * 128 + (wv >> 1) * 64;
    int nt0 = n0 >> 4;

    bool bnv[4]; float bs[4];
#pragma unroll
    for (int ni = 0; ni < 4; ++ni) {
        int nt = nt0 + ni;
        bnv[ni] = (nt < NTB);
        int cc = nt * 16 + col16;
        bs[ni] = (cc < G_) ? bias[cc] : 0.f;
    }

    f32x4 acc[4][4];
#pragma unroll
    for (int mi = 0; mi < 4; ++mi)
#pragma unroll
        for (int ni = 0; ni < 4; ++ni) acc[mi][ni] = (f32x4){0.f, 0.f, 0.f, 0.f};

    bf16x8 z8 = {0, 0, 0, 0, 0, 0, 0, 0};
    bf16x8 a_h0[4], a_l0[4], b_h0[4], b_l0[4];
    bf16x8 a_h1[4], a_l1[4], b_h1[4], b_l1[4];
#pragma unroll
    for (int ni = 0; ni < 4; ++ni) {
        b_h0[ni] = z8; b_l0[ni] = z8; b_h1[ni] = z8; b_l1[ni] = z8;
    }

    LOADK(0, 0);
#pragma unroll 1
    for (int kt = 0; kt < KTN; kt += 2) {
        LOADK(kt + 1, 1);
        MMK(0);
        if (kt + 2 < KTN) { LOADK(kt + 2, 0); }
        MMK(1);
    }

#pragma unroll
    for (int mi = 0; mi < 4; ++mi)
#pragma unroll
        for (int ni = 0; ni < 4; ++ni) {
            int col = n0 + ni * 16 + col16;
            if (col < G_) {
#pragma unroll
                for (int p = 0; p < 4; ++p)
                    C[(size_t)(m0 + mi * 16 + quad * 4 + p) * G_ + col] =
                        acc[mi][ni][p] + bs[ni];
            }
        }
}

// ---------------- legacy fp32 GEMM (fallback path only) ----------------
__global__ __launch_bounds__(256) void k_gemm(const float* __restrict__ A,
                                              const float* __restrict__ BT,
                                              const float* __restrict__ bias,
                                              float* __restrict__ C,
                                              int M, int K) {
    __shared__ __align__(16) float As[16][136];
    __shared__ __align__(16) float Bs[16][68];
    int n0 = blockIdx.x * 64, m0 = blockIdx.y * 128;
    int tid = threadIdx.x;
    int tx = tid & 15, ty = tid >> 4;
    int ar = tid >> 2, ac = (tid & 3) * 4;
    int kr = tid >> 4, nc = (tid & 15) * 4;
    float acc[8][4];
#pragma unroll
    for (int i = 0; i < 8; ++i)
#pragma unroll
        for (int j = 0; j < 4; ++j) acc[i][j] = 0.f;

    for (int k0 = 0; k0 < K; k0 += 16) {
        bool fullK = (k0 + 16 <= K);
#pragma unroll
        for (int half = 0; half < 2; ++half) {
            int m = m0 + ar + half * 64;
            const float* ap = A + (size_t)m * K + k0 + ac;
            if (fullK) {
                v4f v = *(const v4f*)ap;
                As[ac + 0][ar + half * 64] = v.x;
                As[ac + 1][ar + half * 64] = v.y;
                As[ac + 2][ar + half * 64] = v.z;
                As[ac + 3][ar + half * 64] = v.w;
            } else {
#pragma unroll
                for (int i = 0; i < 4; ++i) {
                    int k = k0 + ac + i;
                    As[ac + i][ar + half * 64] = (k < K) ? ap[i] : 0.f;
                }
            }
        }
        {
            int k = k0 + kr, n = n0 + nc;
            if (fullK && n + 3 < G_) {
                v4f v = *(const v4f*)(BT + (size_t)k * G_ + n);
                Bs[kr][nc + 0] = v.x; Bs[kr][nc + 1] = v.y;
                Bs[kr][nc + 2] = v.z; Bs[kr][nc + 3] = v.w;
            } else {
#pragma unroll
                for (int i = 0; i < 4; ++i) {
                    int nn = n + i;
                    Bs[kr][nc + i] = (k < K && nn < G_) ? BT[(size_t)k * G_ + nn] : 0.f;
                }
            }
        }
        __syncthreads();
#pragma unroll
        for (int kk = 0; kk < 16; ++kk) {
            v4f a0 = *(const v4f*)&As[kk][ty * 8];
            v4f a1 = *(const v4f*)&As[kk][ty * 8 + 4];
            v4f b  = *(const v4f*)&Bs[kk][tx * 4];
            const float* af = (const float*)&a0;
            const float* af2 = (const float*)&a1;
            const float* bf = (const float*)&b;
#pragma unroll
            for (int i = 0; i < 4; ++i)
#pragma unroll
                for (int j = 0; j < 4; ++j) {
                    acc[i][j] += af[i] * bf[j];
                    acc[4 + i][j] += af2[i] * bf[j];
                }
        }
        __syncthreads();
    }
    int n = n0 + tx * 4;
    if (n + 3 < G_) {
        v4f bv = *(const v4f*)(bias + n);
#pragma unroll
        for (int i = 0; i < 8; ++i) {
            int m = m0 + ty * 8 + i;
            v4f o = {acc[i][0] + bv.x, acc[i][1] + bv.y, acc[i][2] + bv.z, acc[i][3] + bv.w};
            *(v4f*)(C + (size_t)m * G_ + n) = o;
        }
    } else {
#pragma unroll
        for (int i = 0; i < 8; ++i) {
            int m = m0 + ty * 8 + i;
#pragma unroll
            for (int j = 0; j < 4; ++j)
                if (n + j < G_) C[(size_t)m * G_ + n + j] = acc[i][j] + bias[n + j];
        }
    }
}

// ================= layer-0 scan: xW from X, h out to packed planes =================
struct Combo0 {
    const float* xw;
    const unsigned short* wpk;
    const float* bias;            // gatherIn padding fallback
    unsigned short* phi;          // output plane hi (KAP k-blocks)
    unsigned short* plo;
    int Bn, colOff, bwd, gIn;
};
struct Scan0Args { Combo0 c[4]; const int* inv; int blkStart[5]; };

__global__ __launch_bounds__(TPB) void k_scan0(Scan0Args args) {
    int bx = blockIdx.x, ci = 0;
#pragma unroll
    for (int i = 1; i < 4; ++i)
        if (bx >= args.blkStart[i]) ci = i;
    Combo0 cb = args.c[ci];
    int row0 = (bx - args.blkStart[ci]) * ROWS;

    __shared__ __align__(16) unsigned short hsh[ROWS * HSTR];
    __shared__ __align__(16) unsigned short hsl[ROWS * HSTR];
    __shared__ float cs[ROWS * 152];
    __shared__ float gs[ROWS * GST];
    int tid = threadIdx.x;
    int lane = tid & 63, wv = tid >> 6;
    int col16 = lane & 15, quad = lane >> 4;
    for (int i = tid; i < ROWS * HSTR; i += TPB) { hsh[i] = 0; hsl[i] = 0; }
    for (int i = tid; i < ROWS * 152; i += TPB) cs[i] = 0.f;
    __syncthreads();

    int er[EIT], ej[EIT];
#pragma unroll
    for (int it = 0; it < EIT; ++it) {
        int i = tid + it * TPB;
        er[it] = i / 160;
        ej[it] = i - er[it] * 160;
    }

    for (int s = 0; s < T_; ++s) {
        int t = cb.bwd ? (T_ - 1 - s) : s;

        float xi[EIT], xf_[EIT], xg[EIT], xo[EIT];
#pragma unroll
        for (int it = 0; it < EIT; ++it) {
            int r = er[it], j = ej[it];
            const float* xr;
            if (cb.gIn) {
                int g = args.inv[t * cb.Bn + row0 + r];
                xr = (g >= 0) ? cb.xw + (size_t)g * G_ : cb.bias;
            } else {
                xr = cb.xw + ((size_t)t * cb.Bn + row0 + r) * G_;
            }
            bool act = (j < H_);
            xi[it]  = act ? xr[j] : 0.f;
            xf_[it] = act ? xr[H_ + j] : 0.f;
            xg[it]  = act ? xr[2 * H_ + j] : 0.f;
            xo[it]  = act ? xr[3 * H_ + j] : 0.f;
        }

        bf16x8 ahi[KT_], alo[KT_];
#pragma unroll
        for (int kt = 0; kt < KT_; ++kt) {
            int off = col16 * HSTR + kt * 32 + quad * 8;
            ahi[kt] = *(const bf16x8*)&hsh[off];
            alo[kt] = *(const bf16x8*)&hsl[off];
        }

        for (int nt = wv; nt < NT_; nt += 8) {
            f32x4 a0 = {0.f, 0.f, 0.f, 0.f};
            f32x4 a1 = {0.f, 0.f, 0.f, 0.f};
            const bf16x8* bp = (const bf16x8*)cb.wpk + ((size_t)nt * KT_) * 2 * 64 + lane;
#pragma unroll
            for (int kt = 0; kt < KT_; ++kt) {
                bf16x8 bhi = bp[0];
                bf16x8 blo = bp[64];
                bp += 128;
                if (kt < 3) {
                    a0 = __builtin_amdgcn_mfma_f32_16x16x32_bf16(ahi[kt], bhi, a0, 0, 0, 0);
                    a0 = __builtin_amdgcn_mfma_f32_16x16x32_bf16(ahi[kt], blo, a0, 0, 0, 0);
                    a0 = __builtin_amdgcn_mfma_f32_16x16x32_bf16(alo[kt], bhi, a0, 0, 0, 0);
                } else {
                    a1 = __builtin_amdgcn_mfma_f32_16x16x32_bf16(ahi[kt], bhi, a1, 0, 0, 0);
                    a1 = __builtin_amdgcn_mfma_f32_16x16x32_bf16(ahi[kt], blo, a1, 0, 0, 0);
                    a1 = __builtin_amdgcn_mfma_f32_16x16x32_bf16(alo[kt], bhi, a1, 0, 0, 0);
                }
            }
            f32x4 acc = a0 + a1;
#pragma unroll
            for (int p = 0; p < 4; ++p)
                gs[(quad * 4 + p) * GST + nt * 16 + col16] = acc[p];
        }
        __syncthreads();

        size_t mb = ((size_t)t * cb.Bn + row0) >> 4;
#pragma unroll
        for (int it = 0; it < EIT; ++it) {
            int r = er[it], j = ej[it];
            if (j < H_) {
                float gi = gs[r * GST + j] + xi[it];
                float gf = gs[r * GST + H_ + j] + xf_[it];
                float gg = gs[r * GST + 2 * H_ + j] + xg[it];
                float go = gs[r * GST + 3 * H_ + j] + xo[it];
                float ii = fsig(gi), ff = fsig(gf), oo = fsig(go);
                float cc = ff * cs[r * 152 + j] + ii * ftanh(gg);
                float hh = oo * ftanh(cc);
                cs[r * 152 + j] = cc;
                unsigned u = __float_as_uint(hh);
                unsigned short hi16 = (unsigned short)(u >> 16);
                float hf = __uint_as_float(u & 0xffff0000u);
                unsigned short lo16 = (unsigned short)(__float_as_uint(hh - hf) >> 16);
                hsh[r * HSTR + j] = hi16;
                hsl[r * HSTR + j] = lo16;
                int k = cb.colOff + j;
                size_t off = (mb * KAP + (k >> 3)) * 128 + (size_t)r * 8 + (k & 7);
                cb.phi[off] = hi16;
                cb.plo[off] = lo16;
            }
        }
        __syncthreads();
    }
}

// ================= layer-1 merged scan: fused xW MFMA, direct outputs =============
struct Combo1 {
    const unsigned short* xphi;   // packed x planes (KAP k-blocks of 8)
    const unsigned short* xplo;
    const unsigned short* whh;    // [nt][kt(5)][2][512]
    const unsigned short* wih;    // [kt(10)][nt][2][512]
    const float* bias;            // 600
    float* out;
    int Bn, colOff, bwd, gOut;
};
struct Scan1Args { Combo1 c[4]; const int* inv; int blkStart[5]; };

__global__ __launch_bounds__(TPB) void k_scan1(Scan1Args args) {
    int bx = blockIdx.x, ci = 0;
#pragma unroll
    for (int i = 1; i < 4; ++i)
        if (bx >= args.blkStart[i]) ci = i;
    Combo1 cb = args.c[ci];
    int row0 = (bx - args.blkStart[ci]) * ROWS;

    __shared__ __align__(16) unsigned short hsh[ROWS * HSTR];
    __shared__ __align__(16) unsigned short hsl[ROWS * HSTR];
    __shared__ float cs[ROWS * 152];
    __shared__ float gs[ROWS * GST];
    int tid = threadIdx.x;
    int lane = tid & 63, wv = tid >> 6;
    int col16 = lane & 15, quad = lane >> 4;
    for (int i = tid; i < ROWS * HSTR; i += TPB) { hsh[i] = 0; hsl[i] = 0; }
    for (int i = tid; i < ROWS * 152; i += TPB) cs[i] = 0.f;
    __syncthreads();

    int er[EIT], ej[EIT];
    float bxi[EIT], bxf[EIT], bxg[EIT], bxo[EIT];
#pragma unroll
    for (int it = 0; it < EIT; ++it) {
        int i = tid + it * TPB;
        er[it] = i / 160;
        ej[it] = i - er[it] * 160;
        int j = ej[it];
        bool act = (j < H_);
        bxi[it] = act ? cb.bias[j] : 0.f;
        bxf[it] = act ? cb.bias[H_ + j] : 0.f;
        bxg[it] = act ? cb.bias[2 * H_ + j] : 0.f;
        bxo[it] = act ? cb.bias[3 * H_ + j] : 0.f;
    }

    for (int s = 0; s < T_; ++s) {
        int t = cb.bwd ? (T_ - 1 - s) : s;
        size_t mb = ((size_t)t * cb.Bn + row0) >> 4;

        // ---- x A-fragments from packed global planes (shared across waves) ----
        bf16x8 xh[KTX], xl[KTX];
#pragma unroll
        for (int kt = 0; kt < KTX; ++kt) {
            size_t off = (mb * KAP + kt * 4 + quad) * 128 + (size_t)col16 * 8;
            xh[kt] = *(const bf16x8*)(cb.xphi + off);
            xl[kt] = *(const bf16x8*)(cb.xplo + off);
        }

        // ---- h A-fragments from LDS ----
        bf16x8 ahi[KT_], alo[KT_];
#pragma unroll
        for (int kt = 0; kt < KT_; ++kt) {
            int off = col16 * HSTR + kt * 32 + quad * 8;
            ahi[kt] = *(const bf16x8*)&hsh[off];
            alo[kt] = *(const bf16x8*)&hsl[off];
        }

        // ---- MFMA: gates = h @ Whh^T + x @ Wih^T ----
        for (int nt = wv; nt < NT_; nt += 8) {
            f32x4 a0 = {0.f, 0.f, 0.f, 0.f};
            f32x4 a1 = {0.f, 0.f, 0.f, 0.f};
            const bf16x8* bp = (const bf16x8*)cb.whh + ((size_t)nt * KT_) * 2 * 64 + lane;
#pragma unroll
            for (int kt = 0; kt < KT_; ++kt) {
                bf16x8 bhi = bp[0];
                bf16x8 blo = bp[64];
                bp += 128;
                if (kt < 3) {
                    a0 = __builtin_amdgcn_mfma_f32_16x16x32_bf16(ahi[kt], bhi, a0, 0, 0, 0);
                    a0 = __builtin_amdgcn_mfma_f32_16x16x32_bf16(ahi[kt], blo, a0, 0, 0, 0);
                    a0 = __builtin_amdgcn_mfma_f32_16x16x32_bf16(alo[kt], bhi, a0, 0, 0, 0);
                } else {
                    a1 = __builtin_amdgcn_mfma_f32_16x16x32_bf16(ahi[kt], bhi, a1, 0, 0, 0);
                    a1 = __builtin_amdgcn_mfma_f32_16x16x32_bf16(ahi[kt], blo, a1, 0, 0, 0);
                    a1 = __builtin_amdgcn_mfma_f32_16x16x32_bf16(alo[kt], bhi, a1, 0, 0, 0);
                }
            }
#pragma unroll
            for (int kt = 0; kt < KTX; ++kt) {
                const bf16x8* xp = (const bf16x8*)cb.wih + ((size_t)(kt * NTB + nt) * 2) * 64 + lane;
                bf16x8 bhi = xp[0];
                bf16x8 blo = xp[64];
                if (kt & 1) {
                    a1 = __builtin_amdgcn_mfma_f32_16x16x32_bf16(xh[kt], bhi, a1, 0, 0, 0);
                    a1 = __builtin_amdgcn_mfma_f32_16x16x32_bf16(xh[kt], blo, a1, 0, 0, 0);
                    a1 = __builtin_amdgcn_mfma_f32_16x16x32_bf16(xl[kt], bhi, a1, 0, 0, 0);
                } else {
                    a0 = __builtin_amdgcn_mfma_f32_16x16x32_bf16(xh[kt], bhi, a0, 0, 0, 0);
                    a0 = __builtin_amdgcn_mfma_f32_16x16x32_bf16(xh[kt], blo, a0, 0, 0, 0);
                    a0 = __builtin_amdgcn_mfma_f32_16x16x32_bf16(xl[kt], bhi, a0, 0, 0, 0);
                }
            }
            f32x4 acc = a0 + a1;
#pragma unroll
            for (int p = 0; p < 4; ++p)
                gs[(quad * 4 + p) * GST + nt * 16 + col16] = acc[p];
        }
        __syncthreads();

#pragma unroll
        for (int it = 0; it < EIT; ++it) {
            int r = er[it], j = ej[it];
            if (j < H_) {
                float gi = gs[r * GST + j] + bxi[it];
                float gf = gs[r * GST + H_ + j] + bxf[it];
                float gg = gs[r * GST + 2 * H_ + j] + bxg[it];
                float go = gs[r * GST + 3 * H_ + j] + bxo[it];
                float ii = fsig(gi), ff = fsig(gf), oo = fsig(go);
                float cc = ff * cs[r * 152 + j] + ii * ftanh(gg);
                float hh = oo * ftanh(cc);
                cs[r * 152 + j] = cc;
                unsigned u = __float_as_uint(hh);
                hsh[r * HSTR + j] = (unsigned short)(u >> 16);
                float hf = __uint_as_float(u & 0xffff0000u);
                hsl[r * HSTR + j] = (unsigned short)(__float_as_uint(hh - hf) >> 16);
                if (cb.gOut) {
                    int g = args.inv[t * cb.Bn + row0 + r];
                    if (g >= 0)
                        cb.out[(size_t)g * O_ + cb.colOff + j] = hh;
                } else {
                    cb.out[((size_t)t * cb.Bn + row0 + r) * O_ + cb.colOff + j] = hh;
                }
            }
        }
        __syncthreads();
    }
}

// ---------------- final: out = (out + U_p) * umask (in place) ----------------
__global__ void k_add(float* __restrict__ out, const float* __restrict__ up,
                      const float* __restrict__ um) {
    int idx = blockIdx.x * 256 + threadIdx.x;
    if (idx < T_ * B_ * O_)
        out[idx] = (out[idx] + up[idx]) * um[idx / O_];
}

// ---------------- legacy scan (fallback path) ----------------
struct Combo {
    const float* xw;
    const unsigned short* wpk;
    const float* bias;
    float* out;
    int Bn, colOff, bwd, gIn, gOut;
};
struct ScanArgs {
    Combo c[4];
    const int* inv;
    const float* addSrc;
    const float* umask;
    int blkStart[5];
};

__global__ __launch_bounds__(TPB) void k_scan(ScanArgs args) {
    int bx = blockIdx.x, ci = 0;
#pragma unroll
    for (int i = 1; i < 4; ++i)
        if (bx >= args.blkStart[i]) ci = i;
    Combo cb = args.c[ci];
    int row0 = (bx - args.blkStart[ci]) * ROWS;

    __shared__ __align__(16) unsigned short hsh[ROWS * HSTR];
    __shared__ __align__(16) unsigned short hsl[ROWS * HSTR];
    __shared__ float cs[ROWS * 152];
    __shared__ float gs[ROWS * GST];
    int tid = threadIdx.x;
    int lane = tid & 63, wv = tid >> 6;
    int col16 = lane & 15, quad = lane >> 4;
    for (int i = tid; i < ROWS * HSTR; i += TPB) { hsh[i] = 0; hsl[i] = 0; }
    for (int i = tid; i < ROWS * 152; i += TPB) cs[i] = 0.f;
    __syncthreads();

    int er[EIT], ej[EIT];
#pragma unroll
    for (int it = 0; it < EIT; ++it) {
        int i = tid + it * TPB;
        er[it] = i / 160;
        ej[it] = i - er[it] * 160;
    }

    for (int s = 0; s < T_; ++s) {
        int t = cb.bwd ? (T_ - 1 - s) : s;

        float xi[EIT], xf_[EIT], xg[EIT], xo[EIT];
#pragma unroll
        for (int it = 0; it < EIT; ++it) {
            int r = er[it], j = ej[it];
            const float* xr;
            if (cb.gIn) {
                int g = args.inv[t * cb.Bn + row0 + r];
                xr = (g >= 0) ? cb.xw + (size_t)g * G_ : cb.bias;
            } else {
                xr = cb.xw + ((size_t)t * cb.Bn + row0 + r) * G_;
            }
            bool act = (j < H_);
            xi[it]  = act ? xr[j] : 0.f;
            xf_[it] = act ? xr[H_ + j] : 0.f;
            xg[it]  = act ? xr[2 * H_ + j] : 0.f;
            xo[it]  = act ? xr[3 * H_ + j] : 0.f;
        }

        bf16x8 ahi[KT_], alo[KT_];
#pragma unroll
        for (int kt = 0; kt < KT_; ++kt) {
            int off = col16 * HSTR + kt * 32 + quad * 8;
            ahi[kt] = *(const bf16x8*)&hsh[off];
            alo[kt] = *(const bf16x8*)&hsl[off];
        }

        for (int nt = wv; nt < NT_; nt += 8) {
            f32x4 a0 = {0.f, 0.f, 0.f, 0.f};
            f32x4 a1 = {0.f, 0.f, 0.f, 0.f};
            const bf16x8* bp = (const bf16x8*)cb.wpk + ((size_t)nt * KT_) * 2 * 64 + lane;
#pragma unroll
            for (int kt = 0; kt < KT_; ++kt) {
                bf16x8 bhi = bp[0];
                bf16x8 blo = bp[64];
                bp += 128;
                if (kt < 3) {
                    a0 = __builtin_amdgcn_mfma_f32_16x16x32_bf16(ahi[kt], bhi, a0, 0, 0, 0);
                    a0 = __builtin_amdgcn_mfma_f32_16x16x32_bf16(ahi[kt], blo, a0, 0, 0, 0);
                    a0 = __builtin_amdgcn_mfma_f32_16x16x32_bf16(alo[kt], bhi, a0, 0, 0, 0);
                } else {
                    a1 = __builtin_amdgcn_mfma_f32_16x16x32_bf16(ahi[kt], bhi, a1, 0, 0, 0);
                    a1 = __builtin_amdgcn_mfma_f32_16x16x32_bf16(ahi[kt], blo, a1, 0, 0, 0);
                    a1 = __builtin_amdgcn_mfma_f32_16x16x32_bf16(alo[kt], bhi, a1, 0, 0, 0);
                }
            }
            f32x4 acc = a0 + a1;
#pragma unroll
            for (int p = 0; p < 4; ++p)
                gs[(quad * 4 + p) * GST + nt * 16 + col16] = acc[p];
        }
        __syncthreads();

#pragma unroll
        for (int it = 0; it < EIT; ++it) {
            int r = er[it], j = ej[it];
            if (j < H_) {
                float gi = gs[r * GST + j] + xi[it];
                float gf = gs[r * GST + H_ + j] + xf_[it];
                float gg = gs[r * GST + 2 * H_ + j] + xg[it];
                float go = gs[r * GST + 3 * H_ + j] + xo[it];
                float ii = fsig(gi), ff = fsig(gf), oo = fsig(go);
                float cc = ff * cs[r * 152 + j] + ii * ftanh(gg);
                float hh = oo * ftanh(cc);
                cs[r * 152 + j] = cc;
                unsigned u = __float_as_uint(hh);
                hsh[r * HSTR + j] = (unsigned short)(u >> 16);
                float hf = __uint_as_float(u & 0xffff0000u);
                hsl[r * HSTR + j] = (unsigned short)(__float_as_uint(hh - hf) >> 16);
                if (cb.gOut) {
                    int g = args.inv[t * cb.Bn + row0 + r];
                    if (g >= 0) {
                        size_t o = (size_t)g * O_ + cb.colOff + j;
                        if (args.addSrc)
                            cb.out[o] = (args.addSrc[o] + hh) * args.umask[g];
                        else
                            cb.out[o] = hh;
                    }
                } else {
                    cb.out[((size_t)t * cb.Bn + row0 + r) * O_ + cb.colOff + j] = hh;
                }
            }
        }
        __syncthreads();
    }
}

extern "C" void kernel_launch(void* const* d_in, const int* in_sizes, int n_in,
                              void* d_out, int out_size, void* d_ws, size_t ws_size,
                              hipStream_t stream) {
    const float* U        = (const float*)d_in[0];
    const int*   qmask    = (const int*)d_in[1];
    const float* umask    = (const float*)d_in[2];
    const float* rnn_Wih0 = (const float*)d_in[4];
    const float* rnn_Whh0 = (const float*)d_in[5];
    const float* rnn_b0   = (const float*)d_in[6];
    const float* rnn_Wih1 = (const float*)d_in[7];
    const float* rnn_Whh1 = (const float*)d_in[8];
    const float* rnn_b1   = (const float*)d_in[9];
    const float* pr_Wih0  = (const float*)d_in[10];
    const float* pr_Whh0  = (const float*)d_in[11];
    const float* pr_b0    = (const float*)d_in[12];
    const float* pr_Wih1  = (const float*)d_in[13];
    const float* pr_Whh1  = (const float*)d_in[14];
    const float* pr_b1    = (const float*)d_in[15];

    float* ws = (float*)d_ws;
    dim3 blk(256);
    dim3 sblk(TPB);
    const int INF = 0x7fffffff;

    PackArgs pa;
    for (int d = 0; d < 2; ++d) {
        pa.whh[0 + d] = rnn_Whh0 + (size_t)d * G_ * H_;
        pa.whh[2 + d] = pr_Whh0  + (size_t)d * G_ * H_;
        pa.whh[4 + d] = rnn_Whh1 + (size_t)d * G_ * H_;
        pa.whh[6 + d] = pr_Whh1  + (size_t)d * G_ * H_;
    }
    int packLanes = 8 * NT_ * KT_ * 64;

    if (ws_size >= N_TOTAL * 4ull) {
        // ================= fused MFMA path =================
        int*   inv   = (int*)d_ws + N_INV;
        unsigned short* wpk = (unsigned short*)(ws + N_WPK);
        unsigned short* bw1 = (unsigned short*)(ws + N_BW1);
        unsigned short* hpk = (unsigned short*)(ws + N_HPK);
        unsigned short* rnnHi = hpk;
        unsigned short* rnnLo = rnnHi + RNN_PL;
        unsigned short* prHi  = rnnLo + RNN_PL;
        unsigned short* prLo  = prHi + PR_PL;
        // aliases (dead before scan0 writes planes):
        unsigned short* bw0 = hpk;                         // 4 x BW0_STR shorts
        unsigned short* Uhi = hpk + 4 * BW0_STR;
        unsigned short* Ulo = Uhi + 16777216ull;
        float* X[4];
        for (int i = 0; i < 4; ++i) X[i] = ws + N_X + (size_t)i * 19660800ull;
        float* Uptmp = X[0];                               // alias, live during scan1 only

        k_pos<<<dim3(1), dim3(256), 0, stream>>>(qmask, inv);
        k_pack<<<dim3((packLanes + 255) / 256), dim3(256), 0, stream>>>(pa, wpk);

        // layer-1 Wih fragment packs (own region, persists)
        const float* W1p[4] = {rnn_Wih1, rnn_Wih1 + (size_t)G_ * O_,
                               pr_Wih1,  pr_Wih1 + (size_t)G_ * O_};
        {
            int lanes = KTX * NTB * 64;
            for (int g = 0; g < 4; ++g)
                k_packB<<<dim3((lanes + 255) / 256), blk, 0, stream>>>(
                    W1p[g], O_, KTX, bw1 + (size_t)g * BW1_STR);
        }

        // layer-0 Wih fragment packs (aliased in HPK)
        const float* W0p[4] = {rnn_Wih0, rnn_Wih0 + (size_t)G_ * D_,
                               pr_Wih0,  pr_Wih0 + (size_t)G_ * D_};
        const float* b0p[4] = {rnn_b0, rnn_b0 + G_, pr_b0, pr_b0 + G_};
        {
            int lanes = 32 * NTB * 64;
            for (int g = 0; g < 4; ++g)
                k_packB<<<dim3((lanes + 255) / 256), blk, 0, stream>>>(
                    W0p[g], D_, 32, bw0 + (size_t)g * BW0_STR);
        }

        // layer-0 GEMMs, half-M at a time through packed U planes
        dim3 gm0(5, 128);
        for (int half = 0; half < 2; ++half) {
            k_packU<<<dim3(8192), blk, 0, stream>>>(U + (size_t)half * 16384 * D_, Uhi, Ulo);
            for (int g = 0; g < 4; ++g)
                k_mgemm<0, 32, 128><<<gm0, blk, 0, stream>>>(
                    Uhi, Ulo, nullptr, bw0 + (size_t)g * BW0_STR, b0p[g],
                    X[g] + (size_t)half * 16384 * G_);
        }

        // wipe HPK (kills bw0/Upk aliases, zero-pads planes)
        k_zero<<<dim3((31457280 / 4 + 255) / 256), blk, 0, stream>>>(
            (unsigned int*)hpk, 31457280 / 4);

        // ---- layer-0 scan: 96 blocks -> packed planes ----
        Scan0Args sa = {};
        sa.inv = inv;
        auto set0 = [&](int i, const float* xw, int wslot, const float* bi,
                        unsigned short* phi, unsigned short* plo,
                        int Bn, int co, int bw, int gi) {
            sa.c[i].xw = xw; sa.c[i].wpk = wpk + (size_t)wslot * WPS;
            sa.c[i].bias = bi; sa.c[i].phi = phi; sa.c[i].plo = plo;
            sa.c[i].Bn = Bn; sa.c[i].colOff = co; sa.c[i].bwd = bw; sa.c[i].gIn = gi;
        };
        set0(0, X[0], 0, nullptr, rnnHi, rnnLo, B_, 0, 0, 0);
        set0(1, X[1], 1, nullptr, rnnHi, rnnLo, B_, H_, 1, 0);
        set0(2, X[2], 2, pr_b0 + 0 * G_, prHi, prLo, BP, 0, 0, 1);
        set0(3, X[3], 3, pr_b0 + 1 * G_, prHi, prLo, BP, H_, 1, 1);
        sa.blkStart[0] = 0; sa.blkStart[1] = 16; sa.blkStart[2] = 32;
        sa.blkStart[3] = 64; sa.blkStart[4] = 96;
        k_scan0<<<dim3(96), sblk, 0, stream>>>(sa);

        // ---- merged layer-1 scan: 96 blocks, fused xW ----
        Scan1Args sm = {};
        sm.inv = inv;
        auto set1 = [&](int i, const unsigned short* xh, const unsigned short* xl,
                        int wslot, int bslot, const float* bi, float* o,
                        int Bn, int co, int bw, int go) {
            sm.c[i].xphi = xh; sm.c[i].xplo = xl;
            sm.c[i].whh = wpk + (size_t)wslot * WPS;
            sm.c[i].wih = bw1 + (size_t)bslot * BW1_STR;
            sm.c[i].bias = bi; sm.c[i].out = o;
            sm.c[i].Bn = Bn; sm.c[i].colOff = co; sm.c[i].bwd = bw; sm.c[i].gOut = go;
        };
        set1(0, rnnHi, rnnLo, 4, 0, rnn_b1 + 0 * G_, (float*)d_out, B_, 0, 0, 0);
        set1(1, rnnHi, rnnLo, 5, 1, rnn_b1 + 1 * G_, (float*)d_out, B_, H_, 1, 0);
        set1(2, prHi, prLo, 6, 2, pr_b1 + 0 * G_, Uptmp, BP, 0, 0, 1);
        set1(3, prHi, prLo, 7, 3, pr_b1 + 1 * G_, Uptmp, BP, H_, 1, 1);
        sm.blkStart[0] = 0; sm.blkStart[1] = 16; sm.blkStart[2] = 32;
        sm.blkStart[3] = 64; sm.blkStart[4] = 96;
        k_scan1<<<dim3(96), sblk, 0, stream>>>(sm);

        // ---- out = (emotions + U_p) * umask ----
        k_add<<<dim3((T_ * B_ * O_ + 255) / 256), dim3(256), 0, stream>>>(
            (float*)d_out, Uptmp, umask);
        return;
    }

    // ================= legacy small-workspace fallback =================
    int*   inv   = (int*)d_ws + INV_OFF;
    float* wihT0 = ws + WIHT0_OFF;
    float* wihT1 = ws + WIHT1_OFF;
    unsigned short* wpk = (unsigned short*)(ws + WPK_OFF);
    float* X0    = ws + XW_OFF;
    float* X1    = X0 + XSLOT;
    float* h_rnn = ws + hrnn_off(2);
    float* h_pr  = ws + hpr_off(2);

    const size_t W0S = 1024ull * 600, W1S = 300ull * 600;

    k_pos<<<dim3(1), dim3(256), 0, stream>>>(qmask, inv);
    auto TP = [&](const float* src, float* dst, int K) {
        int total = K * G_;
        k_transpose<<<dim3((total + 255) / 256), dim3(256), 0, stream>>>(src, dst, K);
    };
    for (int d = 0; d < 2; ++d) {
        TP(rnn_Wih0 + (size_t)d * G_ * D_, wihT0 + (0 + d) * W0S, D_);
        TP(pr_Wih0  + (size_t)d * G_ * D_, wihT0 + (2 + d) * W0S, D_);
        TP(rnn_Wih1 + (size_t)d * G_ * O_, wihT1 + (0 + d) * W1S, O_);
        TP(pr_Wih1  + (size_t)d * G_ * O_, wihT1 + (2 + d) * W1S, O_);
    }
    k_pack<<<dim3((packLanes + 255) / 256), dim3(256), 0, stream>>>(pa, wpk);

    ScanArgs z = {};
    auto setCombo = [&](ScanArgs& s2, int i, const float* xw, int wslot,
                        const float* bi, float* o, int Bn, int co, int bw,
                        int gi, int go) {
        s2.c[i].xw = xw; s2.c[i].wpk = wpk + (size_t)wslot * WPS;
        s2.c[i].bias = bi; s2.c[i].out = o;
        s2.c[i].Bn = Bn; s2.c[i].colOff = co; s2.c[i].bwd = bw;
        s2.c[i].gIn = gi; s2.c[i].gOut = go;
    };

    dim3 g32k(10, 256), g64k(10, 512);
    for (int d = 0; d < 2; ++d) {
        k_gemm<<<g32k, blk, 0, stream>>>(U, wihT0 + (0 + d) * W0S, rnn_b0 + d * G_, X0, 32768, D_);
        k_gemm<<<g32k, blk, 0, stream>>>(U, wihT0 + (2 + d) * W0S, pr_b0 + d * G_, X1, 32768, D_);
        ScanArgs sa = z;
        sa.inv = inv;
        setCombo(sa, 0, X0, 0 + d, nullptr, h_rnn, B_, d * H_, d, 0, 0);
        setCombo(sa, 1, X1, 2 + d, pr_b0 + d * G_, h_pr, BP, d * H_, d, 1, 0);
        sa.blkStart[0] = 0; sa.blkStart[1] = 16; sa.blkStart[2] = INF;
        sa.blkStart[3] = INF; sa.blkStart[4] = 48;
        k_scan<<<dim3(48), sblk, 0, stream>>>(sa);
    }
    k_gemm<<<g32k, blk, 0, stream>>>(h_rnn, wihT1 + 0 * W1S, rnn_b1 + 0 * G_, X0, 32768, O_);
    k_gemm<<<g32k, blk, 0, stream>>>(h_rnn, wihT1 + 1 * W1S, rnn_b1 + 1 * G_, X1, 32768, O_);
    {
        ScanArgs sr = z;
        sr.inv = inv;
        setCombo(sr, 0, X0, 4, nullptr, h_rnn, B_, 0, 0, 0, 0);
        setCombo(sr, 1, X1, 5, nullptr, h_rnn, B_, H_, 1, 0, 0);
        sr.blkStart[0] = 0; sr.blkStart[1] = 16; sr.blkStart[2] = INF;
        sr.blkStart[3] = INF; sr.blkStart[4] = 32;
        k_scan<<<dim3(32), sblk, 0, stream>>>(sr);
    }
    for (int d = 0; d < 2; ++d) {
        k_gemm<<<g64k, blk, 0, stream>>>(h_pr, wihT1 + (2 + d) * W1S, pr_b1 + d * G_, X0, 65536, O_);
        ScanArgs sp = z;
        sp.inv = inv; sp.addSrc = h_rnn; sp.umask = umask;
        setCombo(sp, 0, X0, 6 + d, nullptr, (float*)d_out, BP, d * H_, d, 0, 1);
        sp.blkStart[0] = 0; sp.blkStart[1] = INF; sp.blkStart[2] = INF;
        sp.blkStart[3] = INF; sp.blkStart[4] = 32;
        k_scan<<<dim3(32), sblk, 0, stream>>>(sp);
    }
}

// Round 4
// 3733.072 us; speedup vs baseline: 1.4636x; 1.4636x over previous
//
#include <hip/hip_runtime.h>
#include <hip/hip_bf16.h>
#include <math.h>

#define T_ 128
#define B_ 256
#define BP 512     // 2B (party batch)
#define D_ 1024
#define H_ 150
#define G_ 600     // 4H
#define O_ 300     // 2H
#define ROWS 16    // batch rows per scan block (one MFMA M-tile)
#define NT_ 38     // n-tiles of 16 covering 600 (608)
#define KT_ 5      // k-tiles of 32 covering 150 (160)
#define KTX 10     // k-tiles of 32 covering 300 (320) for fused layer-1 xW
#define KAP 40     // layer-1 plane k-blocks of 8 (320/8)
#define HSTR 168   // h hi/lo plane row stride in ushorts
#define GST 620    // gs row stride in floats
#define TPB 512    // scan threads per block (8 waves)
#define EIT 5      // update-phase elems/thread: 16*160/512
#define NTB 38     // GEMM B n-tiles packed

typedef float v4f    __attribute__((ext_vector_type(4)));
typedef short bf16x8 __attribute__((ext_vector_type(8)));
typedef float f32x4  __attribute__((ext_vector_type(4)));
typedef unsigned int u32x4 __attribute__((ext_vector_type(4)));
union HU { u32x4 u; bf16x8 h; };

// ---------------- NEW workspace layout (4-byte words) ----------------
static const size_t N_INV   = 0;                          // 65,536 words
static const size_t N_WPK   = 65536;                      // +778,240
static const size_t N_BW1   = N_WPK + 778240;             // +778,240 (4 x 194,560)
static const size_t N_HPK   = N_BW1 + 778240;             // +31,457,280
static const size_t N_X     = N_HPK + 31457280;           // +78,643,200
static const size_t N_TOTAL = N_X + 78643200 + 256;       // ~446.9 MB

static const size_t WPS      = (size_t)NT_ * KT_ * 2 * 512;  // shorts per Whh combo
static const size_t BW1_STR  = (size_t)KTX * NTB * 2 * 512;  // shorts per L1 Wih combo
static const size_t BW0_STR  = 32ull * NTB * 2 * 512;        // shorts per L0 Wih combo
static const size_t RNN_PL   = 2048ull * KAP * 128;          // 10,485,760 shorts
static const size_t PR_PL    = 4096ull * KAP * 128;          // 20,971,520 shorts

// ---------------- legacy layout (fallback only) ----------------
static const size_t INV_OFF   = 0;
static const size_t WIHT0_OFF = 65536;
static const size_t WIHT1_OFF = WIHT0_OFF + 4ull * 1024 * 600;
static const size_t WPK_OFF   = WIHT1_OFF + 4ull * 300 * 600;
static const size_t WPK_WORDS = 8ull * NT_ * KT_ * 2 * 512 / 2;
static const size_t XW_OFF    = WPK_OFF + WPK_WORDS;
static const size_t XSLOT     = 32768ull * 600;
static size_t hrnn_off(int nslots) { return XW_OFF + (size_t)nslots * XSLOT; }
static size_t hpr_off(int nslots)  { return hrnn_off(nslots) + 32768ull * 300; }

// ---------------- fast transcendentals ----------------
__device__ __forceinline__ float fsig(float x) {
    return __builtin_amdgcn_rcpf(1.f + __expf(-x));
}
__device__ __forceinline__ float ftanh(float x) {
    float xc = fminf(fmaxf(x, -15.f), 15.f);
    float e = __expf(-2.f * xc);
    return (1.f - e) * __builtin_amdgcn_rcpf(1.f + e);
}

// ---------------- inverse map ----------------
__global__ void k_pos(const int* __restrict__ qmask, int* __restrict__ inv) {
    int b = threadIdx.x;
    for (int p = 0; p < T_; ++p) {
        inv[p * BP + b] = -1;
        inv[p * BP + B_ + b] = -1;
    }
    int c0 = 0, c1 = 0;
    for (int t = 0; t < T_; ++t) {
        int s = qmask[(t * B_ + b) * 2 + 1];
        int p = s ? c1++ : c0++;
        inv[p * BP + s * B_ + b] = t * B_ + b;
    }
}

// ---------------- zero a word range ----------------
__global__ void k_zero(unsigned int* __restrict__ p, int n4) {
    int gid = blockIdx.x * 256 + threadIdx.x;
    if (gid < n4) *(u32x4*)(p + (size_t)gid * 4) = (u32x4){0, 0, 0, 0};
}

// ---------------- transpose (legacy fallback) ----------------
__global__ void k_transpose(const float* __restrict__ src, float* __restrict__ dst,
                            int K) {
    int idx = blockIdx.x * 256 + threadIdx.x;
    int total = K * G_;
    if (idx < total) {
        int k = idx / G_, g = idx - k * G_;
        dst[idx] = src[(size_t)g * K + k];
    }
}

// ---------------- pack Whh into scan B-fragment hi/lo layout ----------
struct PackArgs { const float* whh[8]; };
__global__ void k_pack(PackArgs pa, unsigned short* __restrict__ wpk) {
    int gid = blockIdx.x * 256 + threadIdx.x;
    int lane = gid & 63;
    int q = gid >> 6;
    int kt = q % KT_; q /= KT_;
    int nt = q % NT_; q /= NT_;
    if (q >= 8) return;
    const float* W = pa.whh[q];
    int col = nt * 16 + (lane & 15);
    int kbase = kt * 32 + (lane >> 4) * 8;
    size_t base = ((((size_t)q * NT_ + nt) * KT_ + kt) * 2) * 512 + (size_t)lane * 8;
    for (int j = 0; j < 8; ++j) {
        int k = kbase + j;
        float v = (col < G_ && k < H_) ? W[(size_t)col * H_ + k] : 0.f;
        unsigned u = __float_as_uint(v);
        unsigned short hi = (unsigned short)(u >> 16);
        float hf = __uint_as_float(u & 0xffff0000u);
        unsigned short lo = (unsigned short)(__float_as_uint(v - hf) >> 16);
        wpk[base + j] = hi;
        wpk[base + 512 + j] = lo;
    }
}

// ---------------- pack Wih[600][K] into GEMM B-fragment hi/lo layout --------------
__global__ void k_packB(const float* __restrict__ W, int K, int KT,
                        unsigned short* __restrict__ out) {
    int gid = blockIdx.x * 256 + threadIdx.x;
    int lane = gid & 63, q = gid >> 6;
    int kt = q % KT, nt = q / KT;
    if (nt >= NTB) return;
    int col = nt * 16 + (lane & 15);
    int kb = kt * 32 + (lane >> 4) * 8;
    size_t base = ((size_t)(kt * NTB + nt) * 2) * 512 + (size_t)lane * 8;
    bf16x8 h8 = {0, 0, 0, 0, 0, 0, 0, 0};
    bf16x8 l8 = {0, 0, 0, 0, 0, 0, 0, 0};
#pragma unroll
    for (int j = 0; j < 8; ++j) {
        int k = kb + j;
        float v = (col < G_ && k < K) ? W[(size_t)col * K + k] : 0.f;
        unsigned u = __float_as_uint(v);
        h8[j] = (short)(u >> 16);
        float hf = __uint_as_float(u & 0xffff0000u);
        l8[j] = (short)(__float_as_uint(v - hf) >> 16);
    }
    *(bf16x8*)(out + base) = h8;
    *(bf16x8*)(out + base + 512) = l8;
}

// ---------------- pack U half (16384 x 1024) into A-fragment planes ----------
__global__ void k_packU(const float* __restrict__ A, unsigned short* __restrict__ hi,
                        unsigned short* __restrict__ lo) {
    int gid = blockIdx.x * 256 + threadIdx.x;
    int kc = gid & 127, rr = gid >> 7;
    const float* ap = A + (size_t)rr * 1024 + kc * 8;
    size_t off = ((size_t)((rr >> 4) * 128 + kc) * 16 + (rr & 15)) * 8;
    bf16x8 h8, l8;
#pragma unroll
    for (int j = 0; j < 8; ++j) {
        float v = ap[j];
        unsigned u = __float_as_uint(v);
        h8[j] = (short)(u >> 16);
        float hf = __uint_as_float(u & 0xffff0000u);
        l8[j] = (short)(__float_as_uint(v - hf) >> 16);
    }
    *(bf16x8*)(hi + off) = h8;
    *(bf16x8*)(lo + off) = l8;
}

// ---------------- MFMA GEMM (layer 0) ----------
#define LOADK(kt_, S)                                                          \
  {                                                                            \
    if (MODE == 0) {                                                           \
      _Pragma("unroll") for (int mi = 0; mi < 4; ++mi) {                       \
        size_t aoff = ((size_t)((m0 >> 4) + mi) * KA + (kt_) * 4 + quad);      \
        aoff = (aoff * 16 + col16) * 8;                                        \
        a_h##S[mi] = *(const bf16x8*)(Ahi + aoff);                             \
        a_l##S[mi] = *(const bf16x8*)(Alo + aoff);                             \
      }                                                                        \
    } else {                                                                   \
      _Pragma("unroll") for (int mi = 0; mi < 4; ++mi) {                       \
        const unsigned int* ap =                                               \
            Aw + (size_t)(m0 + mi * 16 + col16) * KA + (kt_) * 32 + quad * 8;  \
        u32x4 w0 = *(const u32x4*)ap;                                          \
        u32x4 w1 = *(const u32x4*)(ap + 4);                                    \
        HU hh, ll;                                                             \
        hh.u.x = (w0.x >> 16) | (w0.y & 0xffff0000u);                          \
        hh.u.y = (w0.z >> 16) | (w0.w & 0xffff0000u);                          \
        hh.u.z = (w1.x >> 16) | (w1.y & 0xffff0000u);                          \
        hh.u.w = (w1.z >> 16) | (w1.w & 0xffff0000u);                          \
        ll.u.x = (w0.x & 0xffffu) | (w0.y << 16);                              \
        ll.u.y = (w0.z & 0xffffu) | (w0.w << 16);                              \
        ll.u.z = (w1.x & 0xffffu) | (w1.y << 16);                              \
        ll.u.w = (w1.z & 0xffffu) | (w1.w << 16);                              \
        a_h##S[mi] = hh.h;                                                     \
        a_l##S[mi] = ll.h;                                                     \
      }                                                                        \
    }                                                                          \
    _Pragma("unroll") for (int ni = 0; ni < 4; ++ni) {                         \
      if (bnv[ni]) {                                                           \
        size_t bo = ((size_t)((kt_) * NTB + nt0 + ni) * 2) * 512 + lane * 8;   \
        b_h##S[ni] = *(const bf16x8*)(Bpk + bo);                               \
        b_l##S[ni] = *(const bf16x8*)(Bpk + bo + 512);                         \
      }                                                                        \
    }                                                                          \
  }

#define MMK(S)                                                                 \
  _Pragma("unroll") for (int mi = 0; mi < 4; ++mi)                             \
    _Pragma("unroll") for (int ni = 0; ni < 4; ++ni) {                         \
      acc[mi][ni] = __builtin_amdgcn_mfma_f32_16x16x32_bf16(                   \
          a_h##S[mi], b_h##S[ni], acc[mi][ni], 0, 0, 0);                       \
      acc[mi][ni] = __builtin_amdgcn_mfma_f32_16x16x32_bf16(                   \
          a_h##S[mi], b_l##S[ni], acc[mi][ni], 0, 0, 0);                       \
      acc[mi][ni] = __builtin_amdgcn_mfma_f32_16x16x32_bf16(                   \
          a_l##S[mi], b_h##S[ni], acc[mi][ni], 0, 0, 0);                       \
    }

template<int MODE, int KTN, int KA>
__global__ __launch_bounds__(256) void k_mgemm(const unsigned short* __restrict__ Ahi,
                                               const unsigned short* __restrict__ Alo,
                                               const unsigned int* __restrict__ Aw,
                                               const unsigned short* __restrict__ Bpk,
                                               const float* __restrict__ bias,
                                               float* __restrict__ C) {
    int tid = threadIdx.x, lane = tid & 63, wv = tid >> 6;
    int col16 = lane & 15, quad = lane >> 4;
    int n0 = blockIdx.x * 128 + (wv & 1) * 64;
    int m0 = blockIdx.y * 128 + (wv >> 1) * 64;
    int nt0 = n0 >> 4;

    bool bnv[4]; float bs[4];
#pragma unroll
    for (int ni = 0; ni < 4; ++ni) {
        int nt = nt0 + ni;
        bnv[ni] = (nt < NTB);
        int cc = nt * 16 + col16;
        bs[ni] = (cc < G_) ? bias[cc] : 0.f;
    }

    f32x4 acc[4][4];
#pragma unroll
    for (int mi = 0; mi < 4; ++mi)
#pragma unroll
        for (int ni = 0; ni < 4; ++ni) acc[mi][ni] = (f32x4){0.f, 0.f, 0.f, 0.f};

    bf16x8 z8 = {0, 0, 0, 0, 0, 0, 0, 0};
    bf16x8 a_h0[4], a_l0[4], b_h0[4], b_l0[4];
    bf16x8 a_h1[4], a_l1[4], b_h1[4], b_l1[4];
#pragma unroll
    for (int ni = 0; ni < 4; ++ni) {
        b_h0[ni] = z8; b_l0[ni] = z8; b_h1[ni] = z8; b_l1[ni] = z8;
    }

    LOADK(0, 0);
#pragma unroll 1
    for (int kt = 0; kt < KTN; kt += 2) {
        LOADK(kt + 1, 1);
        MMK(0);
        if (kt + 2 < KTN) { LOADK(kt + 2, 0); }
        MMK(1);
    }

#pragma unroll
    for (int mi = 0; mi < 4; ++mi)
#pragma unroll
        for (int ni = 0; ni < 4; ++ni) {
            int col = n0 + ni * 16 + col16;
            if (col < G_) {
#pragma unroll
                for (int p = 0; p < 4; ++p)
                    C[(size_t)(m0 + mi * 16 + quad * 4 + p) * G_ + col] =
                        acc[mi][ni][p] + bs[ni];
            }
        }
}

// ---------------- legacy fp32 GEMM (fallback path only) ----------------
__global__ __launch_bounds__(256) void k_gemm(const float* __restrict__ A,
                                              const float* __restrict__ BT,
                                              const float* __restrict__ bias,
                                              float* __restrict__ C,
                                              int M, int K) {
    __shared__ __align__(16) float As[16][136];
    __shared__ __align__(16) float Bs[16][68];
    int n0 = blockIdx.x * 64, m0 = blockIdx.y * 128;
    int tid = threadIdx.x;
    int tx = tid & 15, ty = tid >> 4;
    int ar = tid >> 2, ac = (tid & 3) * 4;
    int kr = tid >> 4, nc = (tid & 15) * 4;
    float acc[8][4];
#pragma unroll
    for (int i = 0; i < 8; ++i)
#pragma unroll
        for (int j = 0; j < 4; ++j) acc[i][j] = 0.f;

    for (int k0 = 0; k0 < K; k0 += 16) {
        bool fullK = (k0 + 16 <= K);
#pragma unroll
        for (int half = 0; half < 2; ++half) {
            int m = m0 + ar + half * 64;
            const float* ap = A + (size_t)m * K + k0 + ac;
            if (fullK) {
                v4f v = *(const v4f*)ap;
                As[ac + 0][ar + half * 64] = v.x;
                As[ac + 1][ar + half * 64] = v.y;
                As[ac + 2][ar + half * 64] = v.z;
                As[ac + 3][ar + half * 64] = v.w;
            } else {
#pragma unroll
                for (int i = 0; i < 4; ++i) {
                    int k = k0 + ac + i;
                    As[ac + i][ar + half * 64] = (k < K) ? ap[i] : 0.f;
                }
            }
        }
        {
            int k = k0 + kr, n = n0 + nc;
            if (fullK && n + 3 < G_) {
                v4f v = *(const v4f*)(BT + (size_t)k * G_ + n);
                Bs[kr][nc + 0] = v.x; Bs[kr][nc + 1] = v.y;
                Bs[kr][nc + 2] = v.z; Bs[kr][nc + 3] = v.w;
            } else {
#pragma unroll
                for (int i = 0; i < 4; ++i) {
                    int nn = n + i;
                    Bs[kr][nc + i] = (k < K && nn < G_) ? BT[(size_t)k * G_ + nn] : 0.f;
                }
            }
        }
        __syncthreads();
#pragma unroll
        for (int kk = 0; kk < 16; ++kk) {
            v4f a0 = *(const v4f*)&As[kk][ty * 8];
            v4f a1 = *(const v4f*)&As[kk][ty * 8 + 4];
            v4f b  = *(const v4f*)&Bs[kk][tx * 4];
            const float* af = (const float*)&a0;
            const float* af2 = (const float*)&a1;
            const float* bf = (const float*)&b;
#pragma unroll
            for (int i = 0; i < 4; ++i)
#pragma unroll
                for (int j = 0; j < 4; ++j) {
                    acc[i][j] += af[i] * bf[j];
                    acc[4 + i][j] += af2[i] * bf[j];
                }
        }
        __syncthreads();
    }
    int n = n0 + tx * 4;
    if (n + 3 < G_) {
        v4f bv = *(const v4f*)(bias + n);
#pragma unroll
        for (int i = 0; i < 8; ++i) {
            int m = m0 + ty * 8 + i;
            v4f o = {acc[i][0] + bv.x, acc[i][1] + bv.y, acc[i][2] + bv.z, acc[i][3] + bv.w};
            *(v4f*)(C + (size_t)m * G_ + n) = o;
        }
    } else {
#pragma unroll
        for (int i = 0; i < 8; ++i) {
            int m = m0 + ty * 8 + i;
#pragma unroll
            for (int j = 0; j < 4; ++j)
                if (n + j < G_) C[(size_t)m * G_ + n + j] = acc[i][j] + bias[n + j];
        }
    }
}

// ================= layer-0 scan: xW from X, h out to packed planes =================
struct Combo0 {
    const float* xw;
    const unsigned short* wpk;
    const float* bias;
    unsigned short* phi;
    unsigned short* plo;
    int Bn, colOff, bwd, gIn;
};
struct Scan0Args { Combo0 c[4]; const int* inv; int blkStart[5]; };

__global__ __launch_bounds__(TPB) void k_scan0(Scan0Args args) {
    int bx = blockIdx.x, ci = 0;
#pragma unroll
    for (int i = 1; i < 4; ++i)
        if (bx >= args.blkStart[i]) ci = i;
    Combo0 cb = args.c[ci];
    int row0 = (bx - args.blkStart[ci]) * ROWS;

    __shared__ __align__(16) unsigned short hsh[ROWS * HSTR];
    __shared__ __align__(16) unsigned short hsl[ROWS * HSTR];
    __shared__ float cs[ROWS * 152];
    __shared__ float gs[ROWS * GST];
    int tid = threadIdx.x;
    int lane = tid & 63, wv = tid >> 6;
    int col16 = lane & 15, quad = lane >> 4;
    for (int i = tid; i < ROWS * HSTR; i += TPB) { hsh[i] = 0; hsl[i] = 0; }
    for (int i = tid; i < ROWS * 152; i += TPB) cs[i] = 0.f;
    __syncthreads();

    int er[EIT], ej[EIT];
#pragma unroll
    for (int it = 0; it < EIT; ++it) {
        int i = tid + it * TPB;
        er[it] = i / 160;
        ej[it] = i - er[it] * 160;
    }

    for (int s = 0; s < T_; ++s) {
        int t = cb.bwd ? (T_ - 1 - s) : s;

        float xi[EIT], xf_[EIT], xg[EIT], xo[EIT];
#pragma unroll
        for (int it = 0; it < EIT; ++it) {
            int r = er[it], j = ej[it];
            const float* xr;
            if (cb.gIn) {
                int g = args.inv[t * cb.Bn + row0 + r];
                xr = (g >= 0) ? cb.xw + (size_t)g * G_ : cb.bias;
            } else {
                xr = cb.xw + ((size_t)t * cb.Bn + row0 + r) * G_;
            }
            bool act = (j < H_);
            xi[it]  = act ? xr[j] : 0.f;
            xf_[it] = act ? xr[H_ + j] : 0.f;
            xg[it]  = act ? xr[2 * H_ + j] : 0.f;
            xo[it]  = act ? xr[3 * H_ + j] : 0.f;
        }

        bf16x8 ahi[KT_], alo[KT_];
#pragma unroll
        for (int kt = 0; kt < KT_; ++kt) {
            int off = col16 * HSTR + kt * 32 + quad * 8;
            ahi[kt] = *(const bf16x8*)&hsh[off];
            alo[kt] = *(const bf16x8*)&hsl[off];
        }

        for (int nt = wv; nt < NT_; nt += 8) {
            f32x4 a0 = {0.f, 0.f, 0.f, 0.f};
            f32x4 a1 = {0.f, 0.f, 0.f, 0.f};
            const bf16x8* bp = (const bf16x8*)cb.wpk + ((size_t)nt * KT_) * 2 * 64 + lane;
#pragma unroll
            for (int kt = 0; kt < KT_; ++kt) {
                bf16x8 bhi = bp[0];
                bf16x8 blo = bp[64];
                bp += 128;
                if (kt < 3) {
                    a0 = __builtin_amdgcn_mfma_f32_16x16x32_bf16(ahi[kt], bhi, a0, 0, 0, 0);
                    a0 = __builtin_amdgcn_mfma_f32_16x16x32_bf16(ahi[kt], blo, a0, 0, 0, 0);
                    a0 = __builtin_amdgcn_mfma_f32_16x16x32_bf16(alo[kt], bhi, a0, 0, 0, 0);
                } else {
                    a1 = __builtin_amdgcn_mfma_f32_16x16x32_bf16(ahi[kt], bhi, a1, 0, 0, 0);
                    a1 = __builtin_amdgcn_mfma_f32_16x16x32_bf16(ahi[kt], blo, a1, 0, 0, 0);
                    a1 = __builtin_amdgcn_mfma_f32_16x16x32_bf16(alo[kt], bhi, a1, 0, 0, 0);
                }
            }
            f32x4 acc = a0 + a1;
#pragma unroll
            for (int p = 0; p < 4; ++p)
                gs[(quad * 4 + p) * GST + nt * 16 + col16] = acc[p];
        }
        __syncthreads();

        size_t mb = ((size_t)t * cb.Bn + row0) >> 4;
#pragma unroll
        for (int it = 0; it < EIT; ++it) {
            int r = er[it], j = ej[it];
            if (j < H_) {
                float gi = gs[r * GST + j] + xi[it];
                float gf = gs[r * GST + H_ + j] + xf_[it];
                float gg = gs[r * GST + 2 * H_ + j] + xg[it];
                float go = gs[r * GST + 3 * H_ + j] + xo[it];
                float ii = fsig(gi), ff = fsig(gf), oo = fsig(go);
                float cc = ff * cs[r * 152 + j] + ii * ftanh(gg);
                float hh = oo * ftanh(cc);
                cs[r * 152 + j] = cc;
                unsigned u = __float_as_uint(hh);
                unsigned short hi16 = (unsigned short)(u >> 16);
                float hf = __uint_as_float(u & 0xffff0000u);
                unsigned short lo16 = (unsigned short)(__float_as_uint(hh - hf) >> 16);
                hsh[r * HSTR + j] = hi16;
                hsl[r * HSTR + j] = lo16;
                int k = cb.colOff + j;
                size_t off = (mb * KAP + (k >> 3)) * 128 + (size_t)r * 8 + (k & 7);
                cb.phi[off] = hi16;
                cb.plo[off] = lo16;
            }
        }
        __syncthreads();
    }
}

// ================= layer-1 merged scan: fused xW MFMA, XCD-affine combos ==========
struct Combo1 {
    const unsigned short* xphi;
    const unsigned short* xplo;
    const unsigned short* whh;    // [nt][kt(5)][2][512]
    const unsigned short* wih;    // [kt(10)][nt][2][512]
    const float* bias;
    float* out;
    int Bn, colOff, bwd, gOut;
};
struct Scan1Args {
    Combo1 c[4];
    const int* inv;
    unsigned char mci[96];   // block -> combo (XCD-affine: <=2 combos per XCD lane)
    unsigned char mrb[96];   // block -> row-block within combo
};

__global__ __launch_bounds__(TPB) void k_scan1(Scan1Args args) {
    int bx = blockIdx.x;
    int ci = args.mci[bx];
    Combo1 cb = args.c[ci];
    int row0 = (int)args.mrb[bx] * ROWS;

    __shared__ __align__(16) unsigned short hsh[ROWS * HSTR];
    __shared__ __align__(16) unsigned short hsl[ROWS * HSTR];
    __shared__ float cs[ROWS * 152];
    __shared__ float gs[ROWS * GST];
    int tid = threadIdx.x;
    int lane = tid & 63, wv = tid >> 6;
    int col16 = lane & 15, quad = lane >> 4;
    for (int i = tid; i < ROWS * HSTR; i += TPB) { hsh[i] = 0; hsl[i] = 0; }
    for (int i = tid; i < ROWS * 152; i += TPB) cs[i] = 0.f;
    __syncthreads();

    int er[EIT], ej[EIT];
    float bxi[EIT], bxf[EIT], bxg[EIT], bxo[EIT];
#pragma unroll
    for (int it = 0; it < EIT; ++it) {
        int i = tid + it * TPB;
        er[it] = i / 160;
        ej[it] = i - er[it] * 160;
        int j = ej[it];
        bool act = (j < H_);
        bxi[it] = act ? cb.bias[j] : 0.f;
        bxf[it] = act ? cb.bias[H_ + j] : 0.f;
        bxg[it] = act ? cb.bias[2 * H_ + j] : 0.f;
        bxo[it] = act ? cb.bias[3 * H_ + j] : 0.f;
    }

    for (int s = 0; s < T_; ++s) {
        int t = cb.bwd ? (T_ - 1 - s) : s;
        size_t mb = ((size_t)t * cb.Bn + row0) >> 4;

        // ---- x A-fragments from packed global planes ----
        bf16x8 xh[KTX], xl[KTX];
#pragma unroll
        for (int kt = 0; kt < KTX; ++kt) {
            size_t off = (mb * KAP + kt * 4 + quad) * 128 + (size_t)col16 * 8;
            xh[kt] = *(const bf16x8*)(cb.xphi + off);
            xl[kt] = *(const bf16x8*)(cb.xplo + off);
        }

        // ---- h A-fragments from LDS ----
        bf16x8 ahi[KT_], alo[KT_];
#pragma unroll
        for (int kt = 0; kt < KT_; ++kt) {
            int off = col16 * HSTR + kt * 32 + quad * 8;
            ahi[kt] = *(const bf16x8*)&hsh[off];
            alo[kt] = *(const bf16x8*)&hsl[off];
        }

        // ---- MFMA: gates = h @ Whh^T + x @ Wih^T ----
        for (int nt = wv; nt < NT_; nt += 8) {
            f32x4 a0 = {0.f, 0.f, 0.f, 0.f};
            f32x4 a1 = {0.f, 0.f, 0.f, 0.f};
            const bf16x8* bp = (const bf16x8*)cb.whh + ((size_t)nt * KT_) * 2 * 64 + lane;
#pragma unroll
            for (int kt = 0; kt < KT_; ++kt) {
                bf16x8 bhi = bp[0];
                bf16x8 blo = bp[64];
                bp += 128;
                if (kt < 3) {
                    a0 = __builtin_amdgcn_mfma_f32_16x16x32_bf16(ahi[kt], bhi, a0, 0, 0, 0);
                    a0 = __builtin_amdgcn_mfma_f32_16x16x32_bf16(ahi[kt], blo, a0, 0, 0, 0);
                    a0 = __builtin_amdgcn_mfma_f32_16x16x32_bf16(alo[kt], bhi, a0, 0, 0, 0);
                } else {
                    a1 = __builtin_amdgcn_mfma_f32_16x16x32_bf16(ahi[kt], bhi, a1, 0, 0, 0);
                    a1 = __builtin_amdgcn_mfma_f32_16x16x32_bf16(ahi[kt], blo, a1, 0, 0, 0);
                    a1 = __builtin_amdgcn_mfma_f32_16x16x32_bf16(alo[kt], bhi, a1, 0, 0, 0);
                }
            }
#pragma unroll
            for (int kt = 0; kt < KTX; ++kt) {
                const bf16x8* xp = (const bf16x8*)cb.wih + ((size_t)(kt * NTB + nt) * 2) * 64 + lane;
                bf16x8 bhi = xp[0];
                bf16x8 blo = xp[64];
                if (kt & 1) {
                    a1 = __builtin_amdgcn_mfma_f32_16x16x32_bf16(xh[kt], bhi, a1, 0, 0, 0);
                    a1 = __builtin_amdgcn_mfma_f32_16x16x32_bf16(xh[kt], blo, a1, 0, 0, 0);
                    a1 = __builtin_amdgcn_mfma_f32_16x16x32_bf16(xl[kt], bhi, a1, 0, 0, 0);
                } else {
                    a0 = __builtin_amdgcn_mfma_f32_16x16x32_bf16(xh[kt], bhi, a0, 0, 0, 0);
                    a0 = __builtin_amdgcn_mfma_f32_16x16x32_bf16(xh[kt], blo, a0, 0, 0, 0);
                    a0 = __builtin_amdgcn_mfma_f32_16x16x32_bf16(xl[kt], bhi, a0, 0, 0, 0);
                }
            }
            f32x4 acc = a0 + a1;
#pragma unroll
            for (int p = 0; p < 4; ++p)
                gs[(quad * 4 + p) * GST + nt * 16 + col16] = acc[p];
        }
        __syncthreads();

#pragma unroll
        for (int it = 0; it < EIT; ++it) {
            int r = er[it], j = ej[it];
            if (j < H_) {
                float gi = gs[r * GST + j] + bxi[it];
                float gf = gs[r * GST + H_ + j] + bxf[it];
                float gg = gs[r * GST + 2 * H_ + j] + bxg[it];
                float go = gs[r * GST + 3 * H_ + j] + bxo[it];
                float ii = fsig(gi), ff = fsig(gf), oo = fsig(go);
                float cc = ff * cs[r * 152 + j] + ii * ftanh(gg);
                float hh = oo * ftanh(cc);
                cs[r * 152 + j] = cc;
                unsigned u = __float_as_uint(hh);
                hsh[r * HSTR + j] = (unsigned short)(u >> 16);
                float hf = __uint_as_float(u & 0xffff0000u);
                hsl[r * HSTR + j] = (unsigned short)(__float_as_uint(hh - hf) >> 16);
                if (cb.gOut) {
                    int g = args.inv[t * cb.Bn + row0 + r];
                    if (g >= 0)
                        cb.out[(size_t)g * O_ + cb.colOff + j] = hh;
                } else {
                    cb.out[((size_t)t * cb.Bn + row0 + r) * O_ + cb.colOff + j] = hh;
                }
            }
        }
        __syncthreads();
    }
}

// ---------------- final: out = (out + U_p) * umask (in place) ----------------
__global__ void k_add(float* __restrict__ out, const float* __restrict__ up,
                      const float* __restrict__ um) {
    int idx = blockIdx.x * 256 + threadIdx.x;
    if (idx < T_ * B_ * O_)
        out[idx] = (out[idx] + up[idx]) * um[idx / O_];
}

// ---------------- legacy scan (fallback path) ----------------
struct Combo {
    const float* xw;
    const unsigned short* wpk;
    const float* bias;
    float* out;
    int Bn, colOff, bwd, gIn, gOut;
};
struct ScanArgs {
    Combo c[4];
    const int* inv;
    const float* addSrc;
    const float* umask;
    int blkStart[5];
};

__global__ __launch_bounds__(TPB) void k_scan(ScanArgs args) {
    int bx = blockIdx.x, ci = 0;
#pragma unroll
    for (int i = 1; i < 4; ++i)
        if (bx >= args.blkStart[i]) ci = i;
    Combo cb = args.c[ci];
    int row0 = (bx - args.blkStart[ci]) * ROWS;

    __shared__ __align__(16) unsigned short hsh[ROWS * HSTR];
    __shared__ __align__(16) unsigned short hsl[ROWS * HSTR];
    __shared__ float cs[ROWS * 152];
    __shared__ float gs[ROWS * GST];
    int tid = threadIdx.x;
    int lane = tid & 63, wv = tid >> 6;
    int col16 = lane & 15, quad = lane >> 4;
    for (int i = tid; i < ROWS * HSTR; i += TPB) { hsh[i] = 0; hsl[i] = 0; }
    for (int i = tid; i < ROWS * 152; i += TPB) cs[i] = 0.f;
    __syncthreads();

    int er[EIT], ej[EIT];
#pragma unroll
    for (int it = 0; it < EIT; ++it) {
        int i = tid + it * TPB;
        er[it] = i / 160;
        ej[it] = i - er[it] * 160;
    }

    for (int s = 0; s < T_; ++s) {
        int t = cb.bwd ? (T_ - 1 - s) : s;

        float xi[EIT], xf_[EIT], xg[EIT], xo[EIT];
#pragma unroll
        for (int it = 0; it < EIT; ++it) {
            int r = er[it], j = ej[it];
            const float* xr;
            if (cb.gIn) {
                int g = args.inv[t * cb.Bn + row0 + r];
                xr = (g >= 0) ? cb.xw + (size_t)g * G_ : cb.bias;
            } else {
                xr = cb.xw + ((size_t)t * cb.Bn + row0 + r) * G_;
            }
            bool act = (j < H_);
            xi[it]  = act ? xr[j] : 0.f;
            xf_[it] = act ? xr[H_ + j] : 0.f;
            xg[it]  = act ? xr[2 * H_ + j] : 0.f;
            xo[it]  = act ? xr[3 * H_ + j] : 0.f;
        }

        bf16x8 ahi[KT_], alo[KT_];
#pragma unroll
        for (int kt = 0; kt < KT_; ++kt) {
            int off = col16 * HSTR + kt * 32 + quad * 8;
            ahi[kt] = *(const bf16x8*)&hsh[off];
            alo[kt] = *(const bf16x8*)&hsl[off];
        }

        for (int nt = wv; nt < NT_; nt += 8) {
            f32x4 a0 = {0.f, 0.f, 0.f, 0.f};
            f32x4 a1 = {0.f, 0.f, 0.f, 0.f};
            const bf16x8* bp = (const bf16x8*)cb.wpk + ((size_t)nt * KT_) * 2 * 64 + lane;
#pragma unroll
            for (int kt = 0; kt < KT_; ++kt) {
                bf16x8 bhi = bp[0];
                bf16x8 blo = bp[64];
                bp += 128;
                if (kt < 3) {
                    a0 = __builtin_amdgcn_mfma_f32_16x16x32_bf16(ahi[kt], bhi, a0, 0, 0, 0);
                    a0 = __builtin_amdgcn_mfma_f32_16x16x32_bf16(ahi[kt], blo, a0, 0, 0, 0);
                    a0 = __builtin_amdgcn_mfma_f32_16x16x32_bf16(alo[kt], bhi, a0, 0, 0, 0);
                } else {
                    a1 = __builtin_amdgcn_mfma_f32_16x16x32_bf16(ahi[kt], bhi, a1, 0, 0, 0);
                    a1 = __builtin_amdgcn_mfma_f32_16x16x32_bf16(ahi[kt], blo, a1, 0, 0, 0);
                    a1 = __builtin_amdgcn_mfma_f32_16x16x32_bf16(alo[kt], bhi, a1, 0, 0, 0);
                }
            }
            f32x4 acc = a0 + a1;
#pragma unroll
            for (int p = 0; p < 4; ++p)
                gs[(quad * 4 + p) * GST + nt * 16 + col16] = acc[p];
        }
        __syncthreads();

#pragma unroll
        for (int it = 0; it < EIT; ++it) {
            int r = er[it], j = ej[it];
            if (j < H_) {
                float gi = gs[r * GST + j] + xi[it];
                float gf = gs[r * GST + H_ + j] + xf_[it];
                float gg = gs[r * GST + 2 * H_ + j] + xg[it];
                float go = gs[r * GST + 3 * H_ + j] + xo[it];
                float ii = fsig(gi), ff = fsig(gf), oo = fsig(go);
                float cc = ff * cs[r * 152 + j] + ii * ftanh(gg);
                float hh = oo * ftanh(cc);
                cs[r * 152 + j] = cc;
                unsigned u = __float_as_uint(hh);
                hsh[r * HSTR + j] = (unsigned short)(u >> 16);
                float hf = __uint_as_float(u & 0xffff0000u);
                hsl[r * HSTR + j] = (unsigned short)(__float_as_uint(hh - hf) >> 16);
                if (cb.gOut) {
                    int g = args.inv[t * cb.Bn + row0 + r];
                    if (g >= 0) {
                        size_t o = (size_t)g * O_ + cb.colOff + j;
                        if (args.addSrc)
                            cb.out[o] = (args.addSrc[o] + hh) * args.umask[g];
                        else
                            cb.out[o] = hh;
                    }
                } else {
                    cb.out[((size_t)t * cb.Bn + row0 + r) * O_ + cb.colOff + j] = hh;
                }
            }
        }
        __syncthreads();
    }
}

extern "C" void kernel_launch(void* const* d_in, const int* in_sizes, int n_in,
                              void* d_out, int out_size, void* d_ws, size_t ws_size,
                              hipStream_t stream) {
    const float* U        = (const float*)d_in[0];
    const int*   qmask    = (const int*)d_in[1];
    const float* umask    = (const float*)d_in[2];
    const float* rnn_Wih0 = (const float*)d_in[4];
    const float* rnn_Whh0 = (const float*)d_in[5];
    const float* rnn_b0   = (const float*)d_in[6];
    const float* rnn_Wih1 = (const float*)d_in[7];
    const float* rnn_Whh1 = (const float*)d_in[8];
    const float* rnn_b1   = (const float*)d_in[9];
    const float* pr_Wih0  = (const float*)d_in[10];
    const float* pr_Whh0  = (const float*)d_in[11];
    const float* pr_b0    = (const float*)d_in[12];
    const float* pr_Wih1  = (const float*)d_in[13];
    const float* pr_Whh1  = (const float*)d_in[14];
    const float* pr_b1    = (const float*)d_in[15];

    float* ws = (float*)d_ws;
    dim3 blk(256);
    dim3 sblk(TPB);
    const int INF = 0x7fffffff;

    PackArgs pa;
    for (int d = 0; d < 2; ++d) {
        pa.whh[0 + d] = rnn_Whh0 + (size_t)d * G_ * H_;
        pa.whh[2 + d] = pr_Whh0  + (size_t)d * G_ * H_;
        pa.whh[4 + d] = rnn_Whh1 + (size_t)d * G_ * H_;
        pa.whh[6 + d] = pr_Whh1  + (size_t)d * G_ * H_;
    }
    int packLanes = 8 * NT_ * KT_ * 64;

    if (ws_size >= N_TOTAL * 4ull) {
        // ================= fused MFMA path =================
        int*   inv   = (int*)d_ws + N_INV;
        unsigned short* wpk = (unsigned short*)(ws + N_WPK);
        unsigned short* bw1 = (unsigned short*)(ws + N_BW1);
        unsigned short* hpk = (unsigned short*)(ws + N_HPK);
        unsigned short* rnnHi = hpk;
        unsigned short* rnnLo = rnnHi + RNN_PL;
        unsigned short* prHi  = rnnLo + RNN_PL;
        unsigned short* prLo  = prHi + PR_PL;
        unsigned short* bw0 = hpk;                         // alias, dead before scan0
        unsigned short* Uhi = hpk + 4 * BW0_STR;
        unsigned short* Ulo = Uhi + 16777216ull;
        float* X[4];
        for (int i = 0; i < 4; ++i) X[i] = ws + N_X + (size_t)i * 19660800ull;
        float* Uptmp = X[0];                               // alias, live during scan1 only

        k_pos<<<dim3(1), dim3(256), 0, stream>>>(qmask, inv);
        k_pack<<<dim3((packLanes + 255) / 256), dim3(256), 0, stream>>>(pa, wpk);

        const float* W1p[4] = {rnn_Wih1, rnn_Wih1 + (size_t)G_ * O_,
                               pr_Wih1,  pr_Wih1 + (size_t)G_ * O_};
        {
            int lanes = KTX * NTB * 64;
            for (int g = 0; g < 4; ++g)
                k_packB<<<dim3((lanes + 255) / 256), blk, 0, stream>>>(
                    W1p[g], O_, KTX, bw1 + (size_t)g * BW1_STR);
        }

        const float* W0p[4] = {rnn_Wih0, rnn_Wih0 + (size_t)G_ * D_,
                               pr_Wih0,  pr_Wih0 + (size_t)G_ * D_};
        const float* b0p[4] = {rnn_b0, rnn_b0 + G_, pr_b0, pr_b0 + G_};
        {
            int lanes = 32 * NTB * 64;
            for (int g = 0; g < 4; ++g)
                k_packB<<<dim3((lanes + 255) / 256), blk, 0, stream>>>(
                    W0p[g], D_, 32, bw0 + (size_t)g * BW0_STR);
        }

        dim3 gm0(5, 128);
        for (int half = 0; half < 2; ++half) {
            k_packU<<<dim3(8192), blk, 0, stream>>>(U + (size_t)half * 16384 * D_, Uhi, Ulo);
            for (int g = 0; g < 4; ++g)
                k_mgemm<0, 32, 128><<<gm0, blk, 0, stream>>>(
                    Uhi, Ulo, nullptr, bw0 + (size_t)g * BW0_STR, b0p[g],
                    X[g] + (size_t)half * 16384 * G_);
        }

        // wipe HPK (kills bw0/Upk aliases, zero-pads planes)
        k_zero<<<dim3((31457280 / 4 + 255) / 256), blk, 0, stream>>>(
            (unsigned int*)hpk, 31457280 / 4);

        // ---- layer-0 scan: 96 blocks -> packed planes ----
        Scan0Args sa = {};
        sa.inv = inv;
        auto set0 = [&](int i, const float* xw, int wslot, const float* bi,
                        unsigned short* phi, unsigned short* plo,
                        int Bn, int co, int bw, int gi) {
            sa.c[i].xw = xw; sa.c[i].wpk = wpk + (size_t)wslot * WPS;
            sa.c[i].bias = bi; sa.c[i].phi = phi; sa.c[i].plo = plo;
            sa.c[i].Bn = Bn; sa.c[i].colOff = co; sa.c[i].bwd = bw; sa.c[i].gIn = gi;
        };
        set0(0, X[0], 0, nullptr, rnnHi, rnnLo, B_, 0, 0, 0);
        set0(1, X[1], 1, nullptr, rnnHi, rnnLo, B_, H_, 1, 0);
        set0(2, X[2], 2, pr_b0 + 0 * G_, prHi, prLo, BP, 0, 0, 1);
        set0(3, X[3], 3, pr_b0 + 1 * G_, prHi, prLo, BP, H_, 1, 1);
        sa.blkStart[0] = 0; sa.blkStart[1] = 16; sa.blkStart[2] = 32;
        sa.blkStart[3] = 64; sa.blkStart[4] = 96;
        k_scan0<<<dim3(96), sblk, 0, stream>>>(sa);

        // ---- merged layer-1 scan: 96 blocks, fused xW, XCD-affine combo map ----
        Scan1Args sm = {};
        sm.inv = inv;
        auto set1 = [&](int i, const unsigned short* xh, const unsigned short* xl,
                        int wslot, int bslot, const float* bi, float* o,
                        int Bn, int co, int bw, int go) {
            sm.c[i].xphi = xh; sm.c[i].xplo = xl;
            sm.c[i].whh = wpk + (size_t)wslot * WPS;
            sm.c[i].wih = bw1 + (size_t)bslot * BW1_STR;
            sm.c[i].bias = bi; sm.c[i].out = o;
            sm.c[i].Bn = Bn; sm.c[i].colOff = co; sm.c[i].bwd = bw; sm.c[i].gOut = go;
        };
        set1(0, rnnHi, rnnLo, 4, 0, rnn_b1 + 0 * G_, (float*)d_out, B_, 0, 0, 0);
        set1(1, rnnHi, rnnLo, 5, 1, rnn_b1 + 1 * G_, (float*)d_out, B_, H_, 1, 0);
        set1(2, prHi, prLo, 6, 2, pr_b1 + 0 * G_, Uptmp, BP, 0, 0, 1);
        set1(3, prHi, prLo, 7, 3, pr_b1 + 1 * G_, Uptmp, BP, H_, 1, 1);
        // XCD-lane combo assignment: block bx lands on XCD bx&7 (round-robin).
        // Each lane serves <=2 combos so per-XCD weight set <=2.34MB < 4MB L2.
        {
            static const unsigned char laneAssign[8][12] = {
                {0,0,0,0,0,0,0,0,0,0,0,0},
                {0,0,0,0,1,1,1,1,1,1,1,1},
                {1,1,1,1,1,1,1,1,2,2,2,2},
                {2,2,2,2,2,2,2,2,2,2,2,2},
                {2,2,2,2,2,2,2,2,2,2,2,2},
                {2,2,2,2,3,3,3,3,3,3,3,3},
                {3,3,3,3,3,3,3,3,3,3,3,3},
                {3,3,3,3,3,3,3,3,3,3,3,3},
            };
            int cnt[4] = {0, 0, 0, 0};
            for (int lanex = 0; lanex < 8; ++lanex)
                for (int slot = 0; slot < 12; ++slot) {
                    int bxx = lanex + 8 * slot;
                    int c = laneAssign[lanex][slot];
                    sm.mci[bxx] = (unsigned char)c;
                    sm.mrb[bxx] = (unsigned char)cnt[c]++;
                }
        }
        k_scan1<<<dim3(96), sblk, 0, stream>>>(sm);

        // ---- out = (emotions + U_p) * umask ----
        k_add<<<dim3((T_ * B_ * O_ + 255) / 256), dim3(256), 0, stream>>>(
            (float*)d_out, Uptmp, umask);
        return;
    }

    // ================= legacy small-workspace fallback =================
    int*   inv   = (int*)d_ws + INV_OFF;
    float* wihT0 = ws + WIHT0_OFF;
    float* wihT1 = ws + WIHT1_OFF;
    unsigned short* wpk = (unsigned short*)(ws + WPK_OFF);
    float* X0    = ws + XW_OFF;
    float* X1    = X0 + XSLOT;
    float* h_rnn = ws + hrnn_off(2);
    float* h_pr  = ws + hpr_off(2);

    const size_t W0S = 1024ull * 600, W1S = 300ull * 600;

    k_pos<<<dim3(1), dim3(256), 0, stream>>>(qmask, inv);
    auto TP = [&](const float* src, float* dst, int K) {
        int total = K * G_;
        k_transpose<<<dim3((total + 255) / 256), dim3(256), 0, stream>>>(src, dst, K);
    };
    for (int d = 0; d < 2; ++d) {
        TP(rnn_Wih0 + (size_t)d * G_ * D_, wihT0 + (0 + d) * W0S, D_);
        TP(pr_Wih0  + (size_t)d * G_ * D_, wihT0 + (2 + d) * W0S, D_);
        TP(rnn_Wih1 + (size_t)d * G_ * O_, wihT1 + (0 + d) * W1S, O_);
        TP(pr_Wih1  + (size_t)d * G_ * O_, wihT1 + (2 + d) * W1S, O_);
    }
    k_pack<<<dim3((packLanes + 255) / 256), dim3(256), 0, stream>>>(pa, wpk);

    ScanArgs z = {};
    auto setCombo = [&](ScanArgs& s2, int i, const float* xw, int wslot,
                        const float* bi, float* o, int Bn, int co, int bw,
                        int gi, int go) {
        s2.c[i].xw = xw; s2.c[i].wpk = wpk + (size_t)wslot * WPS;
        s2.c[i].bias = bi; s2.c[i].out = o;
        s2.c[i].Bn = Bn; s2.c[i].colOff = co; s2.c[i].bwd = bw;
        s2.c[i].gIn = gi; s2.c[i].gOut = go;
    };

    dim3 g32k(10, 256), g64k(10, 512);
    for (int d = 0; d < 2; ++d) {
        k_gemm<<<g32k, blk, 0, stream>>>(U, wihT0 + (0 + d) * W0S, rnn_b0 + d * G_, X0, 32768, D_);
        k_gemm<<<g32k, blk, 0, stream>>>(U, wihT0 + (2 + d) * W0S, pr_b0 + d * G_, X1, 32768, D_);
        ScanArgs sa = z;
        sa.inv = inv;
        setCombo(sa, 0, X0, 0 + d, nullptr, h_rnn, B_, d * H_, d, 0, 0);
        setCombo(sa, 1, X1, 2 + d, pr_b0 + d * G_, h_pr, BP, d * H_, d, 1, 0);
        sa.blkStart[0] = 0; sa.blkStart[1] = 16; sa.blkStart[2] = INF;
        sa.blkStart[3] = INF; sa.blkStart[4] = 48;
        k_scan<<<dim3(48), sblk, 0, stream>>>(sa);
    }
    k_gemm<<<g32k, blk, 0, stream>>>(h_rnn, wihT1 + 0 * W1S, rnn_b1 + 0 * G_, X0, 32768, O_);
    k_gemm<<<g32k, blk, 0, stream>>>(h_rnn, wihT1 + 1 * W1S, rnn_b1 + 1 * G_, X1, 32768, O_);
    {
        ScanArgs sr = z;
        sr.inv = inv;
        setCombo(sr, 0, X0, 4, nullptr, h_rnn, B_, 0, 0, 0, 0);
        setCombo(sr, 1, X1, 5, nullptr, h_rnn, B_, H_, 1, 0, 0);
        sr.blkStart[0] = 0; sr.blkStart[1] = 16; sr.blkStart[2] = INF;
        sr.blkStart[3] = INF; sr.blkStart[4] = 32;
        k_scan<<<dim3(32), sblk, 0, stream>>>(sr);
    }
    for (int d = 0; d < 2; ++d) {
        k_gemm<<<g64k, blk, 0, stream>>>(h_pr, wihT1 + (2 + d) * W1S, pr_b1 + d * G_, X0, 65536, O_);
        ScanArgs sp = z;
        sp.inv = inv; sp.addSrc = h_rnn; sp.umask = umask;
        setCombo(sp, 0, X0, 6 + d, nullptr, (float*)d_out, BP, d * H_, d, 0, 1);
        sp.blkStart[0] = 0; sp.blkStart[1] = INF; sp.blkStart[2] = INF;
        sp.blkStart[3] = INF; sp.blkStart[4] = 32;
        k_scan<<<dim3(32), sblk, 0, stream>>>(sp);
    }
}

// Round 5
// 3586.185 us; speedup vs baseline: 1.5235x; 1.0410x over previous
//
#include <hip/hip_runtime.h>
#include <hip/hip_bf16.h>
#include <math.h>

#define T_ 128
#define B_ 256
#define BP 512     // 2B (party batch)
#define D_ 1024
#define H_ 150
#define G_ 600     // 4H
#define O_ 300     // 2H
#define ROWS 16    // batch rows per scan block (one MFMA M-tile)
#define NT_ 38     // n-tiles of 16 covering 600 (608)
#define KT_ 5      // k-tiles of 32 covering 150 (160)
#define KTX 10     // k-tiles of 32 covering 300 (320) for fused layer-1 xW
#define KAP 40     // layer-1 plane k-blocks of 8 (320/8)
#define HSTR 168   // h hi/lo plane row stride in ushorts
#define GST 620    // gs row stride in floats
#define TPB 512    // scan threads per block (8 waves)
#define EIT 5      // update-phase elems/thread: 16*160/512
#define NTB 38     // GEMM B n-tiles packed

typedef float v4f    __attribute__((ext_vector_type(4)));
typedef short bf16x8 __attribute__((ext_vector_type(8)));
typedef float f32x4  __attribute__((ext_vector_type(4)));
typedef unsigned int u32x4 __attribute__((ext_vector_type(4)));
union HU { u32x4 u; bf16x8 h; };

// ---------------- workspace layout (4-byte words) ----------------
static const size_t N_INV   = 0;                          // 65,536 words
static const size_t N_WPK   = 65536;                      // +778,240
static const size_t N_BW1   = N_WPK + 778240;             // +778,240 (4 x 194,560)
static const size_t N_HPK   = N_BW1 + 778240;             // +31,457,280
static const size_t N_X     = N_HPK + 31457280;           // +78,643,200
static const size_t N_TOTAL = N_X + 78643200 + 256;       // ~446.9 MB

static const size_t WPS      = (size_t)NT_ * KT_ * 2 * 512;  // shorts per Whh combo
static const size_t BW1_STR  = (size_t)KTX * NTB * 2 * 512;  // shorts per L1 Wih combo
static const size_t BW0_STR  = 32ull * NTB * 2 * 512;        // shorts per L0 Wih combo
static const size_t RNN_PL   = 2048ull * KAP * 128;          // 10,485,760 shorts
static const size_t PR_PL    = 4096ull * KAP * 128;          // 20,971,520 shorts

// ---------------- legacy layout (fallback only) ----------------
static const size_t INV_OFF   = 0;
static const size_t WIHT0_OFF = 65536;
static const size_t WIHT1_OFF = WIHT0_OFF + 4ull * 1024 * 600;
static const size_t WPK_OFF   = WIHT1_OFF + 4ull * 300 * 600;
static const size_t WPK_WORDS = 8ull * NT_ * KT_ * 2 * 512 / 2;
static const size_t XW_OFF    = WPK_OFF + WPK_WORDS;
static const size_t XSLOT     = 32768ull * 600;
static size_t hrnn_off(int nslots) { return XW_OFF + (size_t)nslots * XSLOT; }
static size_t hpr_off(int nslots)  { return hrnn_off(nslots) + 32768ull * 300; }

// ---------------- fast transcendentals ----------------
__device__ __forceinline__ float fsig(float x) {
    return __builtin_amdgcn_rcpf(1.f + __expf(-x));
}
__device__ __forceinline__ float ftanh(float x) {
    float xc = fminf(fmaxf(x, -15.f), 15.f);
    float e = __expf(-2.f * xc);
    return (1.f - e) * __builtin_amdgcn_rcpf(1.f + e);
}

// ---------------- inverse map ----------------
__global__ void k_pos(const int* __restrict__ qmask, int* __restrict__ inv) {
    int b = threadIdx.x;
    for (int p = 0; p < T_; ++p) {
        inv[p * BP + b] = -1;
        inv[p * BP + B_ + b] = -1;
    }
    int c0 = 0, c1 = 0;
    for (int t = 0; t < T_; ++t) {
        int s = qmask[(t * B_ + b) * 2 + 1];
        int p = s ? c1++ : c0++;
        inv[p * BP + s * B_ + b] = t * B_ + b;
    }
}

// ---------------- zero a word range ----------------
__global__ void k_zero(unsigned int* __restrict__ p, int n4) {
    int gid = blockIdx.x * 256 + threadIdx.x;
    if (gid < n4) *(u32x4*)(p + (size_t)gid * 4) = (u32x4){0, 0, 0, 0};
}

// ---------------- transpose (legacy fallback) ----------------
__global__ void k_transpose(const float* __restrict__ src, float* __restrict__ dst,
                            int K) {
    int idx = blockIdx.x * 256 + threadIdx.x;
    int total = K * G_;
    if (idx < total) {
        int k = idx / G_, g = idx - k * G_;
        dst[idx] = src[(size_t)g * K + k];
    }
}

// ---------------- pack Whh into scan B-fragment hi/lo layout ----------
struct PackArgs { const float* whh[8]; };
__global__ void k_pack(PackArgs pa, unsigned short* __restrict__ wpk) {
    int gid = blockIdx.x * 256 + threadIdx.x;
    int lane = gid & 63;
    int q = gid >> 6;
    int kt = q % KT_; q /= KT_;
    int nt = q % NT_; q /= NT_;
    if (q >= 8) return;
    const float* W = pa.whh[q];
    int col = nt * 16 + (lane & 15);
    int kbase = kt * 32 + (lane >> 4) * 8;
    size_t base = ((((size_t)q * NT_ + nt) * KT_ + kt) * 2) * 512 + (size_t)lane * 8;
    for (int j = 0; j < 8; ++j) {
        int k = kbase + j;
        float v = (col < G_ && k < H_) ? W[(size_t)col * H_ + k] : 0.f;
        unsigned u = __float_as_uint(v);
        unsigned short hi = (unsigned short)(u >> 16);
        float hf = __uint_as_float(u & 0xffff0000u);
        unsigned short lo = (unsigned short)(__float_as_uint(v - hf) >> 16);
        wpk[base + j] = hi;
        wpk[base + 512 + j] = lo;
    }
}

// ---------------- pack Wih[600][K] into GEMM B-fragment hi/lo layout --------------
__global__ void k_packB(const float* __restrict__ W, int K, int KT,
                        unsigned short* __restrict__ out) {
    int gid = blockIdx.x * 256 + threadIdx.x;
    int lane = gid & 63, q = gid >> 6;
    int kt = q % KT, nt = q / KT;
    if (nt >= NTB) return;
    int col = nt * 16 + (lane & 15);
    int kb = kt * 32 + (lane >> 4) * 8;
    size_t base = ((size_t)(kt * NTB + nt) * 2) * 512 + (size_t)lane * 8;
    bf16x8 h8 = {0, 0, 0, 0, 0, 0, 0, 0};
    bf16x8 l8 = {0, 0, 0, 0, 0, 0, 0, 0};
#pragma unroll
    for (int j = 0; j < 8; ++j) {
        int k = kb + j;
        float v = (col < G_ && k < K) ? W[(size_t)col * K + k] : 0.f;
        unsigned u = __float_as_uint(v);
        h8[j] = (short)(u >> 16);
        float hf = __uint_as_float(u & 0xffff0000u);
        l8[j] = (short)(__float_as_uint(v - hf) >> 16);
    }
    *(bf16x8*)(out + base) = h8;
    *(bf16x8*)(out + base + 512) = l8;
}

// ---------------- pack U half (16384 x 1024) into A-fragment planes ----------
__global__ void k_packU(const float* __restrict__ A, unsigned short* __restrict__ hi,
                        unsigned short* __restrict__ lo) {
    int gid = blockIdx.x * 256 + threadIdx.x;
    int kc = gid & 127, rr = gid >> 7;
    const float* ap = A + (size_t)rr * 1024 + kc * 8;
    size_t off = ((size_t)((rr >> 4) * 128 + kc) * 16 + (rr & 15)) * 8;
    bf16x8 h8, l8;
#pragma unroll
    for (int j = 0; j < 8; ++j) {
        float v = ap[j];
        unsigned u = __float_as_uint(v);
        h8[j] = (short)(u >> 16);
        float hf = __uint_as_float(u & 0xffff0000u);
        l8[j] = (short)(__float_as_uint(v - hf) >> 16);
    }
    *(bf16x8*)(hi + off) = h8;
    *(bf16x8*)(lo + off) = l8;
}

// ---------------- MFMA GEMM (layer 0) ----------
#define LOADK(kt_, S)                                                          \
  {                                                                            \
    if (MODE == 0) {                                                           \
      _Pragma("unroll") for (int mi = 0; mi < 4; ++mi) {                       \
        size_t aoff = ((size_t)((m0 >> 4) + mi) * KA + (kt_) * 4 + quad);      \
        aoff = (aoff * 16 + col16) * 8;                                        \
        a_h##S[mi] = *(const bf16x8*)(Ahi + aoff);                             \
        a_l##S[mi] = *(const bf16x8*)(Alo + aoff);                             \
      }                                                                        \
    } else {                                                                   \
      _Pragma("unroll") for (int mi = 0; mi < 4; ++mi) {                       \
        const unsigned int* ap =                                               \
            Aw + (size_t)(m0 + mi * 16 + col16) * KA + (kt_) * 32 + quad * 8;  \
        u32x4 w0 = *(const u32x4*)ap;                                          \
        u32x4 w1 = *(const u32x4*)(ap + 4);                                    \
        HU hh, ll;                                                             \
        hh.u.x = (w0.x >> 16) | (w0.y & 0xffff0000u);                          \
        hh.u.y = (w0.z >> 16) | (w0.w & 0xffff0000u);                          \
        hh.u.z = (w1.x >> 16) | (w1.y & 0xffff0000u);                          \
        hh.u.w = (w1.z >> 16) | (w1.w & 0xffff0000u);                          \
        ll.u.x = (w0.x & 0xffffu) | (w0.y << 16);                              \
        ll.u.y = (w0.z & 0xffffu) | (w0.w << 16);                              \
        ll.u.z = (w1.x & 0xffffu) | (w1.y << 16);                              \
        ll.u.w = (w1.z & 0xffffu) | (w1.w << 16);                              \
        a_h##S[mi] = hh.h;                                                     \
        a_l##S[mi] = ll.h;                                                     \
      }                                                                        \
    }                                                                          \
    _Pragma("unroll") for (int ni = 0; ni < 4; ++ni) {                         \
      if (bnv[ni]) {                                                           \
        size_t bo = ((size_t)((kt_) * NTB + nt0 + ni) * 2) * 512 + lane * 8;   \
        b_h##S[ni] = *(const bf16x8*)(Bpk + bo);                               \
        b_l##S[ni] = *(const bf16x8*)(Bpk + bo + 512);                         \
      }                                                                        \
    }                                                                          \
  }

#define MMK(S)                                                                 \
  _Pragma("unroll") for (int mi = 0; mi < 4; ++mi)                             \
    _Pragma("unroll") for (int ni = 0; ni < 4; ++ni) {                         \
      acc[mi][ni] = __builtin_amdgcn_mfma_f32_16x16x32_bf16(                   \
          a_h##S[mi], b_h##S[ni], acc[mi][ni], 0, 0, 0);                       \
      acc[mi][ni] = __builtin_amdgcn_mfma_f32_16x16x32_bf16(                   \
          a_h##S[mi], b_l##S[ni], acc[mi][ni], 0, 0, 0);                       \
      acc[mi][ni] = __builtin_amdgcn_mfma_f32_16x16x32_bf16(                   \
          a_l##S[mi], b_h##S[ni], acc[mi][ni], 0, 0, 0);                       \
    }

template<int MODE, int KTN, int KA>
__global__ __launch_bounds__(256) void k_mgemm(const unsigned short* __restrict__ Ahi,
                                               const unsigned short* __restrict__ Alo,
                                               const unsigned int* __restrict__ Aw,
                                               const unsigned short* __restrict__ Bpk,
                                               const float* __restrict__ bias,
                                               float* __restrict__ C) {
    int tid = threadIdx.x, lane = tid & 63, wv = tid >> 6;
    int col16 = lane & 15, quad = lane >> 4;
    int n0 = blockIdx.x * 128 + (wv & 1) * 64;
    int m0 = blockIdx.y * 128 + (wv >> 1) * 64;
    int nt0 = n0 >> 4;

    bool bnv[4]; float bs[4];
#pragma unroll
    for (int ni = 0; ni < 4; ++ni) {
        int nt = nt0 + ni;
        bnv[ni] = (nt < NTB);
        int cc = nt * 16 + col16;
        bs[ni] = (cc < G_) ? bias[cc] : 0.f;
    }

    f32x4 acc[4][4];
#pragma unroll
    for (int mi = 0; mi < 4; ++mi)
#pragma unroll
        for (int ni = 0; ni < 4; ++ni) acc[mi][ni] = (f32x4){0.f, 0.f, 0.f, 0.f};

    bf16x8 z8 = {0, 0, 0, 0, 0, 0, 0, 0};
    bf16x8 a_h0[4], a_l0[4], b_h0[4], b_l0[4];
    bf16x8 a_h1[4], a_l1[4], b_h1[4], b_l1[4];
#pragma unroll
    for (int ni = 0; ni < 4; ++ni) {
        b_h0[ni] = z8; b_l0[ni] = z8; b_h1[ni] = z8; b_l1[ni] = z8;
    }

    LOADK(0, 0);
#pragma unroll 1
    for (int kt = 0; kt < KTN; kt += 2) {
        LOADK(kt + 1, 1);
        MMK(0);
        if (kt + 2 < KTN) { LOADK(kt + 2, 0); }
        MMK(1);
    }

#pragma unroll
    for (int mi = 0; mi < 4; ++mi)
#pragma unroll
        for (int ni = 0; ni < 4; ++ni) {
            int col = n0 + ni * 16 + col16;
            if (col < G_) {
#pragma unroll
                for (int p = 0; p < 4; ++p)
                    C[(size_t)(m0 + mi * 16 + quad * 4 + p) * G_ + col] =
                        acc[mi][ni][p] + bs[ni];
            }
        }
}

// ---------------- legacy fp32 GEMM (fallback path only) ----------------
__global__ __launch_bounds__(256) void k_gemm(const float* __restrict__ A,
                                              const float* __restrict__ BT,
                                              const float* __restrict__ bias,
                                              float* __restrict__ C,
                                              int M, int K) {
    __shared__ __align__(16) float As[16][136];
    __shared__ __align__(16) float Bs[16][68];
    int n0 = blockIdx.x * 64, m0 = blockIdx.y * 128;
    int tid = threadIdx.x;
    int tx = tid & 15, ty = tid >> 4;
    int ar = tid >> 2, ac = (tid & 3) * 4;
    int kr = tid >> 4, nc = (tid & 15) * 4;
    float acc[8][4];
#pragma unroll
    for (int i = 0; i < 8; ++i)
#pragma unroll
        for (int j = 0; j < 4; ++j) acc[i][j] = 0.f;

    for (int k0 = 0; k0 < K; k0 += 16) {
        bool fullK = (k0 + 16 <= K);
#pragma unroll
        for (int half = 0; half < 2; ++half) {
            int m = m0 + ar + half * 64;
            const float* ap = A + (size_t)m * K + k0 + ac;
            if (fullK) {
                v4f v = *(const v4f*)ap;
                As[ac + 0][ar + half * 64] = v.x;
                As[ac + 1][ar + half * 64] = v.y;
                As[ac + 2][ar + half * 64] = v.z;
                As[ac + 3][ar + half * 64] = v.w;
            } else {
#pragma unroll
                for (int i = 0; i < 4; ++i) {
                    int k = k0 + ac + i;
                    As[ac + i][ar + half * 64] = (k < K) ? ap[i] : 0.f;
                }
            }
        }
        {
            int k = k0 + kr, n = n0 + nc;
            if (fullK && n + 3 < G_) {
                v4f v = *(const v4f*)(BT + (size_t)k * G_ + n);
                Bs[kr][nc + 0] = v.x; Bs[kr][nc + 1] = v.y;
                Bs[kr][nc + 2] = v.z; Bs[kr][nc + 3] = v.w;
            } else {
#pragma unroll
                for (int i = 0; i < 4; ++i) {
                    int nn = n + i;
                    Bs[kr][nc + i] = (k < K && nn < G_) ? BT[(size_t)k * G_ + nn] : 0.f;
                }
            }
        }
        __syncthreads();
#pragma unroll
        for (int kk = 0; kk < 16; ++kk) {
            v4f a0 = *(const v4f*)&As[kk][ty * 8];
            v4f a1 = *(const v4f*)&As[kk][ty * 8 + 4];
            v4f b  = *(const v4f*)&Bs[kk][tx * 4];
            const float* af = (const float*)&a0;
            const float* af2 = (const float*)&a1;
            const float* bf = (const float*)&b;
#pragma unroll
            for (int i = 0; i < 4; ++i)
#pragma unroll
                for (int j = 0; j < 4; ++j) {
                    acc[i][j] += af[i] * bf[j];
                    acc[4 + i][j] += af2[i] * bf[j];
                }
        }
        __syncthreads();
    }
    int n = n0 + tx * 4;
    if (n + 3 < G_) {
        v4f bv = *(const v4f*)(bias + n);
#pragma unroll
        for (int i = 0; i < 8; ++i) {
            int m = m0 + ty * 8 + i;
            v4f o = {acc[i][0] + bv.x, acc[i][1] + bv.y, acc[i][2] + bv.z, acc[i][3] + bv.w};
            *(v4f*)(C + (size_t)m * G_ + n) = o;
        }
    } else {
#pragma unroll
        for (int i = 0; i < 8; ++i) {
            int m = m0 + ty * 8 + i;
#pragma unroll
            for (int j = 0; j < 4; ++j)
                if (n + j < G_) C[(size_t)m * G_ + n + j] = acc[i][j] + bias[n + j];
        }
    }
}

// ================= layer-0 scan: xW from X, h out to packed planes =================
struct Combo0 {
    const float* xw;
    const unsigned short* wpk;
    const float* bias;
    unsigned short* phi;
    unsigned short* plo;
    int Bn, colOff, bwd, gIn;
};
struct Scan0Args { Combo0 c[4]; const int* inv; int blkStart[5]; };

__global__ __launch_bounds__(TPB) void k_scan0(Scan0Args args) {
    int bx = blockIdx.x, ci = 0;
#pragma unroll
    for (int i = 1; i < 4; ++i)
        if (bx >= args.blkStart[i]) ci = i;
    Combo0 cb = args.c[ci];
    int row0 = (bx - args.blkStart[ci]) * ROWS;

    __shared__ __align__(16) unsigned short hsh[ROWS * HSTR];
    __shared__ __align__(16) unsigned short hsl[ROWS * HSTR];
    __shared__ float cs[ROWS * 152];
    __shared__ float gs[ROWS * GST];
    int tid = threadIdx.x;
    int lane = tid & 63, wv = tid >> 6;
    int col16 = lane & 15, quad = lane >> 4;
    for (int i = tid; i < ROWS * HSTR; i += TPB) { hsh[i] = 0; hsl[i] = 0; }
    for (int i = tid; i < ROWS * 152; i += TPB) cs[i] = 0.f;
    __syncthreads();

    int er[EIT], ej[EIT];
#pragma unroll
    for (int it = 0; it < EIT; ++it) {
        int i = tid + it * TPB;
        er[it] = i / 160;
        ej[it] = i - er[it] * 160;
    }

    for (int s = 0; s < T_; ++s) {
        int t = cb.bwd ? (T_ - 1 - s) : s;

        float xi[EIT], xf_[EIT], xg[EIT], xo[EIT];
#pragma unroll
        for (int it = 0; it < EIT; ++it) {
            int r = er[it], j = ej[it];
            const float* xr;
            if (cb.gIn) {
                int g = args.inv[t * cb.Bn + row0 + r];
                xr = (g >= 0) ? cb.xw + (size_t)g * G_ : cb.bias;
            } else {
                xr = cb.xw + ((size_t)t * cb.Bn + row0 + r) * G_;
            }
            bool act = (j < H_);
            xi[it]  = act ? xr[j] : 0.f;
            xf_[it] = act ? xr[H_ + j] : 0.f;
            xg[it]  = act ? xr[2 * H_ + j] : 0.f;
            xo[it]  = act ? xr[3 * H_ + j] : 0.f;
        }

        bf16x8 ahi[KT_], alo[KT_];
#pragma unroll
        for (int kt = 0; kt < KT_; ++kt) {
            int off = col16 * HSTR + kt * 32 + quad * 8;
            ahi[kt] = *(const bf16x8*)&hsh[off];
            alo[kt] = *(const bf16x8*)&hsl[off];
        }

        for (int nt = wv; nt < NT_; nt += 8) {
            f32x4 a0 = {0.f, 0.f, 0.f, 0.f};
            f32x4 a1 = {0.f, 0.f, 0.f, 0.f};
            const bf16x8* bp = (const bf16x8*)cb.wpk + ((size_t)nt * KT_) * 2 * 64 + lane;
#pragma unroll
            for (int kt = 0; kt < KT_; ++kt) {
                bf16x8 bhi = bp[0];
                bf16x8 blo = bp[64];
                bp += 128;
                if (kt < 3) {
                    a0 = __builtin_amdgcn_mfma_f32_16x16x32_bf16(ahi[kt], bhi, a0, 0, 0, 0);
                    a0 = __builtin_amdgcn_mfma_f32_16x16x32_bf16(ahi[kt], blo, a0, 0, 0, 0);
                    a0 = __builtin_amdgcn_mfma_f32_16x16x32_bf16(alo[kt], bhi, a0, 0, 0, 0);
                } else {
                    a1 = __builtin_amdgcn_mfma_f32_16x16x32_bf16(ahi[kt], bhi, a1, 0, 0, 0);
                    a1 = __builtin_amdgcn_mfma_f32_16x16x32_bf16(ahi[kt], blo, a1, 0, 0, 0);
                    a1 = __builtin_amdgcn_mfma_f32_16x16x32_bf16(alo[kt], bhi, a1, 0, 0, 0);
                }
            }
            f32x4 acc = a0 + a1;
#pragma unroll
            for (int p = 0; p < 4; ++p)
                gs[(quad * 4 + p) * GST + nt * 16 + col16] = acc[p];
        }
        __syncthreads();

        size_t mb = ((size_t)t * cb.Bn + row0) >> 4;
#pragma unroll
        for (int it = 0; it < EIT; ++it) {
            int r = er[it], j = ej[it];
            if (j < H_) {
                float gi = gs[r * GST + j] + xi[it];
                float gf = gs[r * GST + H_ + j] + xf_[it];
                float gg = gs[r * GST + 2 * H_ + j] + xg[it];
                float go = gs[r * GST + 3 * H_ + j] + xo[it];
                float ii = fsig(gi), ff = fsig(gf), oo = fsig(go);
                float cc = ff * cs[r * 152 + j] + ii * ftanh(gg);
                float hh = oo * ftanh(cc);
                cs[r * 152 + j] = cc;
                unsigned u = __float_as_uint(hh);
                unsigned short hi16 = (unsigned short)(u >> 16);
                float hf = __uint_as_float(u & 0xffff0000u);
                unsigned short lo16 = (unsigned short)(__float_as_uint(hh - hf) >> 16);
                hsh[r * HSTR + j] = hi16;
                hsl[r * HSTR + j] = lo16;
                int k = cb.colOff + j;
                size_t off = (mb * KAP + (k >> 3)) * 128 + (size_t)r * 8 + (k & 7);
                cb.phi[off] = hi16;
                cb.plo[off] = lo16;
            }
        }
        __syncthreads();
    }
}

// ================= layer-1 merged scan: fused xW MFMA, XCD-affine combos ==========
// restructured: x-MFMAs in independent acc chains issued before h-dependent whh
// chain; x-activation fragments prefetched one step ahead (latency hides under
// the update phase).
struct Combo1 {
    const unsigned short* xphi;
    const unsigned short* xplo;
    const unsigned short* whh;    // [nt][kt(5)][2][512]
    const unsigned short* wih;    // [kt(10)][nt][2][512]
    const float* bias;
    float* out;
    int Bn, colOff, bwd, gOut;
};
struct Scan1Args {
    Combo1 c[4];
    const int* inv;
    unsigned char mci[96];   // block -> combo (XCD-affine: <=2 combos per XCD lane)
    unsigned char mrb[96];   // block -> row-block within combo
};

__global__ __launch_bounds__(TPB) void k_scan1(Scan1Args args) {
    int bx = blockIdx.x;
    int ci = args.mci[bx];
    Combo1 cb = args.c[ci];
    int row0 = (int)args.mrb[bx] * ROWS;

    __shared__ __align__(16) unsigned short hsh[ROWS * HSTR];
    __shared__ __align__(16) unsigned short hsl[ROWS * HSTR];
    __shared__ float cs[ROWS * 152];
    __shared__ float gs[ROWS * GST];
    int tid = threadIdx.x;
    int lane = tid & 63, wv = tid >> 6;
    int col16 = lane & 15, quad = lane >> 4;
    for (int i = tid; i < ROWS * HSTR; i += TPB) { hsh[i] = 0; hsl[i] = 0; }
    for (int i = tid; i < ROWS * 152; i += TPB) cs[i] = 0.f;
    __syncthreads();

    int er[EIT], ej[EIT];
    float bxi[EIT], bxf[EIT], bxg[EIT], bxo[EIT];
#pragma unroll
    for (int it = 0; it < EIT; ++it) {
        int i = tid + it * TPB;
        er[it] = i / 160;
        ej[it] = i - er[it] * 160;
        int j = ej[it];
        bool act = (j < H_);
        bxi[it] = act ? cb.bias[j] : 0.f;
        bxf[it] = act ? cb.bias[H_ + j] : 0.f;
        bxg[it] = act ? cb.bias[2 * H_ + j] : 0.f;
        bxo[it] = act ? cb.bias[3 * H_ + j] : 0.f;
    }

    // ---- prologue: load x A-fragments for s = 0 ----
    bf16x8 xh[KTX], xl[KTX];
    {
        int t0 = cb.bwd ? (T_ - 1) : 0;
        size_t mb0 = ((size_t)t0 * cb.Bn + row0) >> 4;
#pragma unroll
        for (int kt = 0; kt < KTX; ++kt) {
            size_t off = (mb0 * KAP + kt * 4 + quad) * 128 + (size_t)col16 * 8;
            xh[kt] = *(const bf16x8*)(cb.xphi + off);
            xl[kt] = *(const bf16x8*)(cb.xplo + off);
        }
    }

    for (int s = 0; s < T_; ++s) {
        int t = cb.bwd ? (T_ - 1 - s) : s;

        // ---- h A-fragments from LDS (issue early; waited by whh MFMAs) ----
        bf16x8 ahi[KT_], alo[KT_];
#pragma unroll
        for (int kt = 0; kt < KT_; ++kt) {
            int off = col16 * HSTR + kt * 32 + quad * 8;
            ahi[kt] = *(const bf16x8*)&hsh[off];
            alo[kt] = *(const bf16x8*)&hsl[off];
        }

        // ---- MFMA: x @ Wih^T first (indep chains), then h @ Whh^T ----
        for (int nt = wv; nt < NT_; nt += 8) {
            f32x4 ax0 = {0.f, 0.f, 0.f, 0.f};
            f32x4 ax1 = {0.f, 0.f, 0.f, 0.f};
#pragma unroll
            for (int kt = 0; kt < KTX; ++kt) {
                const bf16x8* xp = (const bf16x8*)cb.wih + ((size_t)(kt * NTB + nt) * 2) * 64 + lane;
                bf16x8 bhi = xp[0];
                bf16x8 blo = xp[64];
                if (kt & 1) {
                    ax1 = __builtin_amdgcn_mfma_f32_16x16x32_bf16(xh[kt], bhi, ax1, 0, 0, 0);
                    ax1 = __builtin_amdgcn_mfma_f32_16x16x32_bf16(xh[kt], blo, ax1, 0, 0, 0);
                    ax1 = __builtin_amdgcn_mfma_f32_16x16x32_bf16(xl[kt], bhi, ax1, 0, 0, 0);
                } else {
                    ax0 = __builtin_amdgcn_mfma_f32_16x16x32_bf16(xh[kt], bhi, ax0, 0, 0, 0);
                    ax0 = __builtin_amdgcn_mfma_f32_16x16x32_bf16(xh[kt], blo, ax0, 0, 0, 0);
                    ax0 = __builtin_amdgcn_mfma_f32_16x16x32_bf16(xl[kt], bhi, ax0, 0, 0, 0);
                }
            }
            f32x4 a0 = {0.f, 0.f, 0.f, 0.f};
            f32x4 a1 = {0.f, 0.f, 0.f, 0.f};
            const bf16x8* bp = (const bf16x8*)cb.whh + ((size_t)nt * KT_) * 2 * 64 + lane;
#pragma unroll
            for (int kt = 0; kt < KT_; ++kt) {
                bf16x8 bhi = bp[0];
                bf16x8 blo = bp[64];
                bp += 128;
                if (kt < 3) {
                    a0 = __builtin_amdgcn_mfma_f32_16x16x32_bf16(ahi[kt], bhi, a0, 0, 0, 0);
                    a0 = __builtin_amdgcn_mfma_f32_16x16x32_bf16(ahi[kt], blo, a0, 0, 0, 0);
                    a0 = __builtin_amdgcn_mfma_f32_16x16x32_bf16(alo[kt], bhi, a0, 0, 0, 0);
                } else {
                    a1 = __builtin_amdgcn_mfma_f32_16x16x32_bf16(ahi[kt], bhi, a1, 0, 0, 0);
                    a1 = __builtin_amdgcn_mfma_f32_16x16x32_bf16(ahi[kt], blo, a1, 0, 0, 0);
                    a1 = __builtin_amdgcn_mfma_f32_16x16x32_bf16(alo[kt], bhi, a1, 0, 0, 0);
                }
            }
            f32x4 acc = (ax0 + ax1) + (a0 + a1);
#pragma unroll
            for (int p = 0; p < 4; ++p)
                gs[(quad * 4 + p) * GST + nt * 16 + col16] = acc[p];
        }
        __syncthreads();

        // ---- prefetch x A-fragments for s+1 (latency hides under update) ----
        if (s + 1 < T_) {
            int tn = cb.bwd ? (T_ - 2 - s) : (s + 1);
            size_t mbn = ((size_t)tn * cb.Bn + row0) >> 4;
#pragma unroll
            for (int kt = 0; kt < KTX; ++kt) {
                size_t off = (mbn * KAP + kt * 4 + quad) * 128 + (size_t)col16 * 8;
                xh[kt] = *(const bf16x8*)(cb.xphi + off);
                xl[kt] = *(const bf16x8*)(cb.xplo + off);
            }
        }

        // ---- gate combine + state update + output ----
#pragma unroll
        for (int it = 0; it < EIT; ++it) {
            int r = er[it], j = ej[it];
            if (j < H_) {
                float gi = gs[r * GST + j] + bxi[it];
                float gf = gs[r * GST + H_ + j] + bxf[it];
                float gg = gs[r * GST + 2 * H_ + j] + bxg[it];
                float go = gs[r * GST + 3 * H_ + j] + bxo[it];
                float ii = fsig(gi), ff = fsig(gf), oo = fsig(go);
                float cc = ff * cs[r * 152 + j] + ii * ftanh(gg);
                float hh = oo * ftanh(cc);
                cs[r * 152 + j] = cc;
                unsigned u = __float_as_uint(hh);
                hsh[r * HSTR + j] = (unsigned short)(u >> 16);
                float hf = __uint_as_float(u & 0xffff0000u);
                hsl[r * HSTR + j] = (unsigned short)(__float_as_uint(hh - hf) >> 16);
                if (cb.gOut) {
                    int g = args.inv[t * cb.Bn + row0 + r];
                    if (g >= 0)
                        cb.out[(size_t)g * O_ + cb.colOff + j] = hh;
                } else {
                    cb.out[((size_t)t * cb.Bn + row0 + r) * O_ + cb.colOff + j] = hh;
                }
            }
        }
        __syncthreads();
    }
}

// ---------------- final: out = (out + U_p) * umask (in place) ----------------
__global__ void k_add(float* __restrict__ out, const float* __restrict__ up,
                      const float* __restrict__ um) {
    int idx = blockIdx.x * 256 + threadIdx.x;
    if (idx < T_ * B_ * O_)
        out[idx] = (out[idx] + up[idx]) * um[idx / O_];
}

// ---------------- legacy scan (fallback path) ----------------
struct Combo {
    const float* xw;
    const unsigned short* wpk;
    const float* bias;
    float* out;
    int Bn, colOff, bwd, gIn, gOut;
};
struct ScanArgs {
    Combo c[4];
    const int* inv;
    const float* addSrc;
    const float* umask;
    int blkStart[5];
};

__global__ __launch_bounds__(TPB) void k_scan(ScanArgs args) {
    int bx = blockIdx.x, ci = 0;
#pragma unroll
    for (int i = 1; i < 4; ++i)
        if (bx >= args.blkStart[i]) ci = i;
    Combo cb = args.c[ci];
    int row0 = (bx - args.blkStart[ci]) * ROWS;

    __shared__ __align__(16) unsigned short hsh[ROWS * HSTR];
    __shared__ __align__(16) unsigned short hsl[ROWS * HSTR];
    __shared__ float cs[ROWS * 152];
    __shared__ float gs[ROWS * GST];
    int tid = threadIdx.x;
    int lane = tid & 63, wv = tid >> 6;
    int col16 = lane & 15, quad = lane >> 4;
    for (int i = tid; i < ROWS * HSTR; i += TPB) { hsh[i] = 0; hsl[i] = 0; }
    for (int i = tid; i < ROWS * 152; i += TPB) cs[i] = 0.f;
    __syncthreads();

    int er[EIT], ej[EIT];
#pragma unroll
    for (int it = 0; it < EIT; ++it) {
        int i = tid + it * TPB;
        er[it] = i / 160;
        ej[it] = i - er[it] * 160;
    }

    for (int s = 0; s < T_; ++s) {
        int t = cb.bwd ? (T_ - 1 - s) : s;

        float xi[EIT], xf_[EIT], xg[EIT], xo[EIT];
#pragma unroll
        for (int it = 0; it < EIT; ++it) {
            int r = er[it], j = ej[it];
            const float* xr;
            if (cb.gIn) {
                int g = args.inv[t * cb.Bn + row0 + r];
                xr = (g >= 0) ? cb.xw + (size_t)g * G_ : cb.bias;
            } else {
                xr = cb.xw + ((size_t)t * cb.Bn + row0 + r) * G_;
            }
            bool act = (j < H_);
            xi[it]  = act ? xr[j] : 0.f;
            xf_[it] = act ? xr[H_ + j] : 0.f;
            xg[it]  = act ? xr[2 * H_ + j] : 0.f;
            xo[it]  = act ? xr[3 * H_ + j] : 0.f;
        }

        bf16x8 ahi[KT_], alo[KT_];
#pragma unroll
        for (int kt = 0; kt < KT_; ++kt) {
            int off = col16 * HSTR + kt * 32 + quad * 8;
            ahi[kt] = *(const bf16x8*)&hsh[off];
            alo[kt] = *(const bf16x8*)&hsl[off];
        }

        for (int nt = wv; nt < NT_; nt += 8) {
            f32x4 a0 = {0.f, 0.f, 0.f, 0.f};
            f32x4 a1 = {0.f, 0.f, 0.f, 0.f};
            const bf16x8* bp = (const bf16x8*)cb.wpk + ((size_t)nt * KT_) * 2 * 64 + lane;
#pragma unroll
            for (int kt = 0; kt < KT_; ++kt) {
                bf16x8 bhi = bp[0];
                bf16x8 blo = bp[64];
                bp += 128;
                if (kt < 3) {
                    a0 = __builtin_amdgcn_mfma_f32_16x16x32_bf16(ahi[kt], bhi, a0, 0, 0, 0);
                    a0 = __builtin_amdgcn_mfma_f32_16x16x32_bf16(ahi[kt], blo, a0, 0, 0, 0);
                    a0 = __builtin_amdgcn_mfma_f32_16x16x32_bf16(alo[kt], bhi, a0, 0, 0, 0);
                } else {
                    a1 = __builtin_amdgcn_mfma_f32_16x16x32_bf16(ahi[kt], bhi, a1, 0, 0, 0);
                    a1 = __builtin_amdgcn_mfma_f32_16x16x32_bf16(ahi[kt], blo, a1, 0, 0, 0);
                    a1 = __builtin_amdgcn_mfma_f32_16x16x32_bf16(alo[kt], bhi, a1, 0, 0, 0);
                }
            }
            f32x4 acc = a0 + a1;
#pragma unroll
            for (int p = 0; p < 4; ++p)
                gs[(quad * 4 + p) * GST + nt * 16 + col16] = acc[p];
        }
        __syncthreads();

#pragma unroll
        for (int it = 0; it < EIT; ++it) {
            int r = er[it], j = ej[it];
            if (j < H_) {
                float gi = gs[r * GST + j] + xi[it];
                float gf = gs[r * GST + H_ + j] + xf_[it];
                float gg = gs[r * GST + 2 * H_ + j] + xg[it];
                float go = gs[r * GST + 3 * H_ + j] + xo[it];
                float ii = fsig(gi), ff = fsig(gf), oo = fsig(go);
                float cc = ff * cs[r * 152 + j] + ii * ftanh(gg);
                float hh = oo * ftanh(cc);
                cs[r * 152 + j] = cc;
                unsigned u = __float_as_uint(hh);
                hsh[r * HSTR + j] = (unsigned short)(u >> 16);
                float hf = __uint_as_float(u & 0xffff0000u);
                hsl[r * HSTR + j] = (unsigned short)(__float_as_uint(hh - hf) >> 16);
                if (cb.gOut) {
                    int g = args.inv[t * cb.Bn + row0 + r];
                    if (g >= 0) {
                        size_t o = (size_t)g * O_ + cb.colOff + j;
                        if (args.addSrc)
                            cb.out[o] = (args.addSrc[o] + hh) * args.umask[g];
                        else
                            cb.out[o] = hh;
                    }
                } else {
                    cb.out[((size_t)t * cb.Bn + row0 + r) * O_ + cb.colOff + j] = hh;
                }
            }
        }
        __syncthreads();
    }
}

extern "C" void kernel_launch(void* const* d_in, const int* in_sizes, int n_in,
                              void* d_out, int out_size, void* d_ws, size_t ws_size,
                              hipStream_t stream) {
    const float* U        = (const float*)d_in[0];
    const int*   qmask    = (const int*)d_in[1];
    const float* umask    = (const float*)d_in[2];
    const float* rnn_Wih0 = (const float*)d_in[4];
    const float* rnn_Whh0 = (const float*)d_in[5];
    const float* rnn_b0   = (const float*)d_in[6];
    const float* rnn_Wih1 = (const float*)d_in[7];
    const float* rnn_Whh1 = (const float*)d_in[8];
    const float* rnn_b1   = (const float*)d_in[9];
    const float* pr_Wih0  = (const float*)d_in[10];
    const float* pr_Whh0  = (const float*)d_in[11];
    const float* pr_b0    = (const float*)d_in[12];
    const float* pr_Wih1  = (const float*)d_in[13];
    const float* pr_Whh1  = (const float*)d_in[14];
    const float* pr_b1    = (const float*)d_in[15];

    float* ws = (float*)d_ws;
    dim3 blk(256);
    dim3 sblk(TPB);
    const int INF = 0x7fffffff;

    PackArgs pa;
    for (int d = 0; d < 2; ++d) {
        pa.whh[0 + d] = rnn_Whh0 + (size_t)d * G_ * H_;
        pa.whh[2 + d] = pr_Whh0  + (size_t)d * G_ * H_;
        pa.whh[4 + d] = rnn_Whh1 + (size_t)d * G_ * H_;
        pa.whh[6 + d] = pr_Whh1  + (size_t)d * G_ * H_;
    }
    int packLanes = 8 * NT_ * KT_ * 64;

    if (ws_size >= N_TOTAL * 4ull) {
        // ================= fused MFMA path =================
        int*   inv   = (int*)d_ws + N_INV;
        unsigned short* wpk = (unsigned short*)(ws + N_WPK);
        unsigned short* bw1 = (unsigned short*)(ws + N_BW1);
        unsigned short* hpk = (unsigned short*)(ws + N_HPK);
        unsigned short* rnnHi = hpk;
        unsigned short* rnnLo = rnnHi + RNN_PL;
        unsigned short* prHi  = rnnLo + RNN_PL;
        unsigned short* prLo  = prHi + PR_PL;
        unsigned short* bw0 = hpk;                         // alias, dead before scan0
        unsigned short* Uhi = hpk + 4 * BW0_STR;
        unsigned short* Ulo = Uhi + 16777216ull;
        float* X[4];
        for (int i = 0; i < 4; ++i) X[i] = ws + N_X + (size_t)i * 19660800ull;
        float* Uptmp = X[0];                               // alias, live during scan1 only

        k_pos<<<dim3(1), dim3(256), 0, stream>>>(qmask, inv);
        k_pack<<<dim3((packLanes + 255) / 256), dim3(256), 0, stream>>>(pa, wpk);

        const float* W1p[4] = {rnn_Wih1, rnn_Wih1 + (size_t)G_ * O_,
                               pr_Wih1,  pr_Wih1 + (size_t)G_ * O_};
        {
            int lanes = KTX * NTB * 64;
            for (int g = 0; g < 4; ++g)
                k_packB<<<dim3((lanes + 255) / 256), blk, 0, stream>>>(
                    W1p[g], O_, KTX, bw1 + (size_t)g * BW1_STR);
        }

        const float* W0p[4] = {rnn_Wih0, rnn_Wih0 + (size_t)G_ * D_,
                               pr_Wih0,  pr_Wih0 + (size_t)G_ * D_};
        const float* b0p[4] = {rnn_b0, rnn_b0 + G_, pr_b0, pr_b0 + G_};
        {
            int lanes = 32 * NTB * 64;
            for (int g = 0; g < 4; ++g)
                k_packB<<<dim3((lanes + 255) / 256), blk, 0, stream>>>(
                    W0p[g], D_, 32, bw0 + (size_t)g * BW0_STR);
        }

        dim3 gm0(5, 128);
        for (int half = 0; half < 2; ++half) {
            k_packU<<<dim3(8192), blk, 0, stream>>>(U + (size_t)half * 16384 * D_, Uhi, Ulo);
            for (int g = 0; g < 4; ++g)
                k_mgemm<0, 32, 128><<<gm0, blk, 0, stream>>>(
                    Uhi, Ulo, nullptr, bw0 + (size_t)g * BW0_STR, b0p[g],
                    X[g] + (size_t)half * 16384 * G_);
        }

        // wipe HPK (kills bw0/Upk aliases, zero-pads planes)
        k_zero<<<dim3((31457280 / 4 + 255) / 256), blk, 0, stream>>>(
            (unsigned int*)hpk, 31457280 / 4);

        // ---- layer-0 scan: 96 blocks -> packed planes ----
        Scan0Args sa = {};
        sa.inv = inv;
        auto set0 = [&](int i, const float* xw, int wslot, const float* bi,
                        unsigned short* phi, unsigned short* plo,
                        int Bn, int co, int bw, int gi) {
            sa.c[i].xw = xw; sa.c[i].wpk = wpk + (size_t)wslot * WPS;
            sa.c[i].bias = bi; sa.c[i].phi = phi; sa.c[i].plo = plo;
            sa.c[i].Bn = Bn; sa.c[i].colOff = co; sa.c[i].bwd = bw; sa.c[i].gIn = gi;
        };
        set0(0, X[0], 0, nullptr, rnnHi, rnnLo, B_, 0, 0, 0);
        set0(1, X[1], 1, nullptr, rnnHi, rnnLo, B_, H_, 1, 0);
        set0(2, X[2], 2, pr_b0 + 0 * G_, prHi, prLo, BP, 0, 0, 1);
        set0(3, X[3], 3, pr_b0 + 1 * G_, prHi, prLo, BP, H_, 1, 1);
        sa.blkStart[0] = 0; sa.blkStart[1] = 16; sa.blkStart[2] = 32;
        sa.blkStart[3] = 64; sa.blkStart[4] = 96;
        k_scan0<<<dim3(96), sblk, 0, stream>>>(sa);

        // ---- merged layer-1 scan: 96 blocks, fused xW, XCD-affine combo map ----
        Scan1Args sm = {};
        sm.inv = inv;
        auto set1 = [&](int i, const unsigned short* xh, const unsigned short* xl,
                        int wslot, int bslot, const float* bi, float* o,
                        int Bn, int co, int bw, int go) {
            sm.c[i].xphi = xh; sm.c[i].xplo = xl;
            sm.c[i].whh = wpk + (size_t)wslot * WPS;
            sm.c[i].wih = bw1 + (size_t)bslot * BW1_STR;
            sm.c[i].bias = bi; sm.c[i].out = o;
            sm.c[i].Bn = Bn; sm.c[i].colOff = co; sm.c[i].bwd = bw; sm.c[i].gOut = go;
        };
        set1(0, rnnHi, rnnLo, 4, 0, rnn_b1 + 0 * G_, (float*)d_out, B_, 0, 0, 0);
        set1(1, rnnHi, rnnLo, 5, 1, rnn_b1 + 1 * G_, (float*)d_out, B_, H_, 1, 0);
        set1(2, prHi, prLo, 6, 2, pr_b1 + 0 * G_, Uptmp, BP, 0, 0, 1);
        set1(3, prHi, prLo, 7, 3, pr_b1 + 1 * G_, Uptmp, BP, H_, 1, 1);
        // XCD-lane combo assignment: block bx lands on XCD bx&7 (round-robin).
        // Each lane serves <=2 combos so per-XCD weight set <=2.34MB < 4MB L2.
        {
            static const unsigned char laneAssign[8][12] = {
                {0,0,0,0,0,0,0,0,0,0,0,0},
                {0,0,0,0,1,1,1,1,1,1,1,1},
                {1,1,1,1,1,1,1,1,2,2,2,2},
                {2,2,2,2,2,2,2,2,2,2,2,2},
                {2,2,2,2,2,2,2,2,2,2,2,2},
                {2,2,2,2,3,3,3,3,3,3,3,3},
                {3,3,3,3,3,3,3,3,3,3,3,3},
                {3,3,3,3,3,3,3,3,3,3,3,3},
            };
            int cnt[4] = {0, 0, 0, 0};
            for (int lanex = 0; lanex < 8; ++lanex)
                for (int slot = 0; slot < 12; ++slot) {
                    int bxx = lanex + 8 * slot;
                    int c = laneAssign[lanex][slot];
                    sm.mci[bxx] = (unsigned char)c;
                    sm.mrb[bxx] = (unsigned char)cnt[c]++;
                }
        }
        k_scan1<<<dim3(96), sblk, 0, stream>>>(sm);

        // ---- out = (emotions + U_p) * umask ----
        k_add<<<dim3((T_ * B_ * O_ + 255) / 256), dim3(256), 0, stream>>>(
            (float*)d_out, Uptmp, umask);
        return;
    }

    // ================= legacy small-workspace fallback =================
    int*   inv   = (int*)d_ws + INV_OFF;
    float* wihT0 = ws + WIHT0_OFF;
    float* wihT1 = ws + WIHT1_OFF;
    unsigned short* wpk = (unsigned short*)(ws + WPK_OFF);
    float* X0    = ws + XW_OFF;
    float* X1    = X0 + XSLOT;
    float* h_rnn = ws + hrnn_off(2);
    float* h_pr  = ws + hpr_off(2);

    const size_t W0S = 1024ull * 600, W1S = 300ull * 600;

    k_pos<<<dim3(1), dim3(256), 0, stream>>>(qmask, inv);
    auto TP = [&](const float* src, float* dst, int K) {
        int total = K * G_;
        k_transpose<<<dim3((total + 255) / 256), dim3(256), 0, stream>>>(src, dst, K);
    };
    for (int d = 0; d < 2; ++d) {
        TP(rnn_Wih0 + (size_t)d * G_ * D_, wihT0 + (0 + d) * W0S, D_);
        TP(pr_Wih0  + (size_t)d * G_ * D_, wihT0 + (2 + d) * W0S, D_);
        TP(rnn_Wih1 + (size_t)d * G_ * O_, wihT1 + (0 + d) * W1S, O_);
        TP(pr_Wih1  + (size_t)d * G_ * O_, wihT1 + (2 + d) * W1S, O_);
    }
    k_pack<<<dim3((packLanes + 255) / 256), dim3(256), 0, stream>>>(pa, wpk);

    ScanArgs z = {};
    auto setCombo = [&](ScanArgs& s2, int i, const float* xw, int wslot,
                        const float* bi, float* o, int Bn, int co, int bw,
                        int gi, int go) {
        s2.c[i].xw = xw; s2.c[i].wpk = wpk + (size_t)wslot * WPS;
        s2.c[i].bias = bi; s2.c[i].out = o;
        s2.c[i].Bn = Bn; s2.c[i].colOff = co; s2.c[i].bwd = bw;
        s2.c[i].gIn = gi; s2.c[i].gOut = go;
    };

    dim3 g32k(10, 256), g64k(10, 512);
    for (int d = 0; d < 2; ++d) {
        k_gemm<<<g32k, blk, 0, stream>>>(U, wihT0 + (0 + d) * W0S, rnn_b0 + d * G_, X0, 32768, D_);
        k_gemm<<<g32k, blk, 0, stream>>>(U, wihT0 + (2 + d) * W0S, pr_b0 + d * G_, X1, 32768, D_);
        ScanArgs sa = z;
        sa.inv = inv;
        setCombo(sa, 0, X0, 0 + d, nullptr, h_rnn, B_, d * H_, d, 0, 0);
        setCombo(sa, 1, X1, 2 + d, pr_b0 + d * G_, h_pr, BP, d * H_, d, 1, 0);
        sa.blkStart[0] = 0; sa.blkStart[1] = 16; sa.blkStart[2] = INF;
        sa.blkStart[3] = INF; sa.blkStart[4] = 48;
        k_scan<<<dim3(48), sblk, 0, stream>>>(sa);
    }
    k_gemm<<<g32k, blk, 0, stream>>>(h_rnn, wihT1 + 0 * W1S, rnn_b1 + 0 * G_, X0, 32768, O_);
    k_gemm<<<g32k, blk, 0, stream>>>(h_rnn, wihT1 + 1 * W1S, rnn_b1 + 1 * G_, X1, 32768, O_);
    {
        ScanArgs sr = z;
        sr.inv = inv;
        setCombo(sr, 0, X0, 4, nullptr, h_rnn, B_, 0, 0, 0, 0);
        setCombo(sr, 1, X1, 5, nullptr, h_rnn, B_, H_, 1, 0, 0);
        sr.blkStart[0] = 0; sr.blkStart[1] = 16; sr.blkStart[2] = INF;
        sr.blkStart[3] = INF; sr.blkStart[4] = 32;
        k_scan<<<dim3(32), sblk, 0, stream>>>(sr);
    }
    for (int d = 0; d < 2; ++d) {
        k_gemm<<<g64k, blk, 0, stream>>>(h_pr, wihT1 + (2 + d) * W1S, pr_b1 + d * G_, X0, 65536, O_);
        ScanArgs sp = z;
        sp.inv = inv; sp.addSrc = h_rnn; sp.umask = umask;
        setCombo(sp, 0, X0, 6 + d, nullptr, (float*)d_out, BP, d * H_, d, 0, 1);
        sp.blkStart[0] = 0; sp.blkStart[1] = INF; sp.blkStart[2] = INF;
        sp.blkStart[3] = INF; sp.blkStart[4] = 32;
        k_scan<<<dim3(32), sblk, 0, stream>>>(sp);
    }
}